// Round 8
// baseline (457.237 us; speedup 1.0000x reference)
//
#include <hip/hip_runtime.h>

#define NN 50000
#define NE 600000
#define DD 128
#define NH 4

#define SCAN_T 512
#define SCAN_B ((NN + SCAN_T - 1) / SCAN_T)   // 98 blocks

typedef short s16x8 __attribute__((ext_vector_type(8)));
typedef float f32x4 __attribute__((ext_vector_type(4)));

// fp32 -> bf16 (RNE) and back
__device__ __forceinline__ unsigned short bfh(float f) {
  unsigned u = __float_as_uint(f);
  return (unsigned short)((u + 0x7fffu + ((u >> 16) & 1u)) >> 16);
}
__device__ __forceinline__ float bff(unsigned short h) {
  return __uint_as_float(((unsigned)h) << 16);
}

// ---------- CSR build ----------
__global__ void count_deg(const int* __restrict__ ei, int* __restrict__ deg) {
  int e = blockIdx.x * 256 + threadIdx.x;
  if (e < NE) atomicAdd(deg + ei[NE + e], 1);
}

__global__ __launch_bounds__(SCAN_T) void scan_partial(
    const int* __restrict__ deg, int* __restrict__ rowp, int* __restrict__ bsum) {
  __shared__ int buf[SCAN_T];
  int b = blockIdx.x, t = threadIdx.x;
  int i = b * SCAN_T + t;
  int v = (i < NN) ? deg[i] : 0;
  buf[t] = v;
  __syncthreads();
  for (int o = 1; o < SCAN_T; o <<= 1) {
    int add = (t >= o) ? buf[t - o] : 0;
    __syncthreads();
    buf[t] += add;
    __syncthreads();
  }
  if (i < NN) rowp[i] = buf[t] - v;
  if (t == SCAN_T - 1) bsum[b] = buf[t];
}

__global__ __launch_bounds__(128) void scan_bsums(
    int* __restrict__ bsum, int* __restrict__ boff, int* __restrict__ rowp) {
  __shared__ int buf[128];
  int t = threadIdx.x;
  int v = (t < SCAN_B) ? bsum[t] : 0;
  buf[t] = v;
  __syncthreads();
  for (int o = 1; o < 128; o <<= 1) {
    int add = (t >= o) ? buf[t - o] : 0;
    __syncthreads();
    buf[t] += add;
    __syncthreads();
  }
  if (t < SCAN_B) boff[t] = buf[t] - v;
  if (t == 127) rowp[NN] = buf[t];
}

__global__ __launch_bounds__(SCAN_T) void scan_add(
    int* __restrict__ rowp, const int* __restrict__ boff) {
  int b = blockIdx.x, t = threadIdx.x;
  int i = b * SCAN_T + t;
  if (i < NN) rowp[i] += boff[b];
}

__global__ void scatter_src(const int* __restrict__ ei, const int* __restrict__ rowp,
                            int* __restrict__ cur, int* __restrict__ colsrc) {
  int e = blockIdx.x * 256 + threadIdx.x;
  if (e < NE) {
    int d = ei[NE + e];
    int p = atomicAdd(cur + d, 1);
    colsrc[rowp[d] + p] = ei[e];
  }
}

// ---------- W prep: transpose + split fp32 -> bf16 hi/mid ----------
// wt layout: [N=256][K=128], cols 0..127 = Wl, 128..255 = Wr
__global__ __launch_bounds__(256) void prep_w(
    const float* __restrict__ Wl, const float* __restrict__ Wr,
    unsigned short* __restrict__ wth, unsigned short* __restrict__ wtm) {
  int idx = blockIdx.x * 256 + threadIdx.x;
  if (idx >= 256 * 128) return;
  int n = idx >> 7, k = idx & 127;
  float w = (n < 128) ? Wl[(size_t)k * 128 + n] : Wr[(size_t)k * 128 + (n - 128)];
  unsigned short hi = bfh(w);
  wth[idx] = hi;
  wtm[idx] = bfh(w - bff(hi));
}

// ---------- dual GEMM via split-bf16 MFMA (3-term, ~fp32 accuracy) ----------
// block: 16 rows x 256 cols, 4 waves; wave: 16x64 via 4x mfma_f32_16x16x32_bf16.
// Fragment k-map (m89/m162-derived): elem e -> k = (e>>2)*16 + 4*(lane>>4) + (e&3).
__global__ __launch_bounds__(256) void dual_gemm_mfma(
    const float* __restrict__ h, const unsigned short* __restrict__ wth,
    const unsigned short* __restrict__ wtm, const float* __restrict__ blv,
    const float* __restrict__ brv, float* __restrict__ xl, float* __restrict__ xr) {
  const int tid = threadIdx.x;
  const int lane = tid & 63;
  const int wv = tid >> 6;
  const int lr = lane & 15;
  const int g = lane >> 4;
  const int row = blockIdx.x * 16 + lr;

  // A fragments: load fp32 row direct from global, split to bf16 hi/mid
  s16x8 ah[4], am[4];
  const float* hrow = h + (size_t)row * DD;
#pragma unroll
  for (int c = 0; c < 4; c++) {
    float4 f0 = *(const float4*)(hrow + c * 32 + 4 * g);
    float4 f1 = *(const float4*)(hrow + c * 32 + 16 + 4 * g);
    float fs0[4] = {f0.x, f0.y, f0.z, f0.w};
    float fs1[4] = {f1.x, f1.y, f1.z, f1.w};
#pragma unroll
    for (int e = 0; e < 4; e++) {
      unsigned short h0 = bfh(fs0[e]);
      ah[c][e] = (short)h0;
      am[c][e] = (short)bfh(fs0[e] - bff(h0));
      unsigned short h1 = bfh(fs1[e]);
      ah[c][e + 4] = (short)h1;
      am[c][e + 4] = (short)bfh(fs1[e] - bff(h1));
    }
  }

  f32x4 acc[4];
#pragma unroll
  for (int nt = 0; nt < 4; nt++)
#pragma unroll
    for (int e = 0; e < 4; e++) acc[nt][e] = 0.f;

#pragma unroll
  for (int nt = 0; nt < 4; nt++) {
    const int col = wv * 64 + nt * 16 + lr;
    const unsigned short* bh = wth + (size_t)col * DD;
    const unsigned short* bm = wtm + (size_t)col * DD;
#pragma unroll
    for (int c = 0; c < 4; c++) {
      ushort4 bh0 = *(const ushort4*)(bh + c * 32 + 4 * g);
      ushort4 bh1 = *(const ushort4*)(bh + c * 32 + 16 + 4 * g);
      ushort4 bm0 = *(const ushort4*)(bm + c * 32 + 4 * g);
      ushort4 bm1 = *(const ushort4*)(bm + c * 32 + 16 + 4 * g);
      s16x8 bhi, bmi;
      bhi[0] = (short)bh0.x; bhi[1] = (short)bh0.y; bhi[2] = (short)bh0.z; bhi[3] = (short)bh0.w;
      bhi[4] = (short)bh1.x; bhi[5] = (short)bh1.y; bhi[6] = (short)bh1.z; bhi[7] = (short)bh1.w;
      bmi[0] = (short)bm0.x; bmi[1] = (short)bm0.y; bmi[2] = (short)bm0.z; bmi[3] = (short)bm0.w;
      bmi[4] = (short)bm1.x; bmi[5] = (short)bm1.y; bmi[6] = (short)bm1.z; bmi[7] = (short)bm1.w;
      acc[nt] = __builtin_amdgcn_mfma_f32_16x16x32_bf16(ah[c], bhi, acc[nt], 0, 0, 0);
      acc[nt] = __builtin_amdgcn_mfma_f32_16x16x32_bf16(ah[c], bmi, acc[nt], 0, 0, 0);
      acc[nt] = __builtin_amdgcn_mfma_f32_16x16x32_bf16(am[c], bhi, acc[nt], 0, 0, 0);
    }
  }

  // epilogue: C row = base + 4*g + reg, col = lane&15 within tile; + bias
  const int rbase = blockIdx.x * 16 + 4 * g;
#pragma unroll
  for (int nt = 0; nt < 4; nt++) {
    int col = wv * 64 + nt * 16 + lr;
    float bv = (col < DD) ? blv[col] : brv[col - DD];
    float* dst = (col < DD) ? (xl + col) : (xr + (col - DD));
#pragma unroll
    for (int r = 0; r < 4; r++) {
      dst[(size_t)(rbase + r) * DD] = acc[nt][r] + bv;
    }
  }
}

// ---------- fused edge path, chunk-4 online softmax ----------
__global__ __launch_bounds__(256) void fused_edge_agg(
    const int* __restrict__ rowp, const int* __restrict__ colsrc,
    const float* __restrict__ xl, const float* __restrict__ xr,
    const float* __restrict__ att, const float* __restrict__ bias,
    const float* __restrict__ gam, const float* __restrict__ bet,
    float* __restrict__ out) {
  int node = (blockIdx.x * 256 + threadIdx.x) >> 6;
  if (node >= NN) return;
  int lane = threadIdx.x & 63;
  int c = lane << 1;                 // dims c, c+1 (head = lane>>4)
  float2 xrv = *(const float2*)(xr + (size_t)node * DD + c);
  float2 atv = *(const float2*)(att + c);
  int j0 = rowp[node], j1 = rowp[node + 1];

  float m = -INFINITY, den = 0.f, ax = 0.f, ay = 0.f;

  for (int j = j0; j < j1; j += 4) {
    int n = j1 - j; if (n > 4) n = 4;
    float2 xv[4];
    float p[4];
#pragma unroll
    for (int k = 0; k < 4; k++) { xv[k] = make_float2(0.f, 0.f); p[k] = -INFINITY; }
#pragma unroll
    for (int k = 0; k < 4; k++) {
      if (k < n) {
        int s = colsrc[j + k];
        xv[k] = *(const float2*)(xl + (size_t)s * DD + c);
      }
    }
#pragma unroll
    for (int k = 0; k < 4; k++) {
      if (k < n) {
        float vx = xv[k].x + xrv.x, vy = xv[k].y + xrv.y;
        vx = vx > 0.f ? vx : 0.2f * vx;      // leaky_relu NEG=0.2
        vy = vy > 0.f ? vy : 0.2f * vy;
        float pp = vx * atv.x + vy * atv.y;
        pp += __shfl_xor(pp, 1);
        pp += __shfl_xor(pp, 2);
        pp += __shfl_xor(pp, 4);
        pp += __shfl_xor(pp, 8);             // per-head (16-lane) total
        p[k] = pp;
      }
    }
    float m4 = fmaxf(fmaxf(p[0], p[1]), fmaxf(p[2], p[3]));
    float w0 = __expf(p[0] - m4), w1 = __expf(p[1] - m4);
    float w2 = __expf(p[2] - m4), w3 = __expf(p[3] - m4);
    float sw = (w0 + w1) + (w2 + w3);
    float sx = (w0 * xv[0].x + w1 * xv[1].x) + (w2 * xv[2].x + w3 * xv[3].x);
    float sy = (w0 * xv[0].y + w1 * xv[1].y) + (w2 * xv[2].y + w3 * xv[3].y);
    float mn = fmaxf(m, m4);
    float a = __expf(m - mn);
    float b = __expf(m4 - mn);
    den = den * a + sw * b;
    ax  = ax * a + sx * b;
    ay  = ay * a + sy * b;
    m = mn;
  }

  float inv = 1.f / (den + 1e-16f);
  float vx = ax * inv + bias[c];
  float vy = ay * inv + bias[c + 1];
  float s1 = vx + vy, s2 = vx * vx + vy * vy;
#pragma unroll
  for (int o = 1; o < 64; o <<= 1) { s1 += __shfl_xor(s1, o); s2 += __shfl_xor(s2, o); }
  float mean = s1 * (1.f / 128.f);
  float var = s2 * (1.f / 128.f) - mean * mean;
  float rstd = rsqrtf(var + 1e-5f);
  float nx = (vx - mean) * rstd * gam[c] + bet[c];
  float ny = (vy - mean) * rstd * gam[c + 1] + bet[c + 1];
  out[(size_t)node * DD + c]     = nx > 0.f ? nx : expf(nx) - 1.f;
  out[(size_t)node * DD + c + 1] = ny > 0.f ? ny : expf(ny) - 1.f;
}

extern "C" void kernel_launch(void* const* d_in, const int* in_sizes, int n_in,
                              void* d_out, int out_size, void* d_ws, size_t ws_size,
                              hipStream_t stream) {
  const float* x  = (const float*)d_in[0];
  const int*   ei = (const int*)d_in[1];
  const float* Wl[2]   = {(const float*)d_in[2],  (const float*)d_in[10]};
  const float* bl[2]   = {(const float*)d_in[3],  (const float*)d_in[11]};
  const float* Wr[2]   = {(const float*)d_in[4],  (const float*)d_in[12]};
  const float* br[2]   = {(const float*)d_in[5],  (const float*)d_in[13]};
  const float* att[2]  = {(const float*)d_in[6],  (const float*)d_in[14]};
  const float* bias[2] = {(const float*)d_in[7],  (const float*)d_in[15]};
  const float* gam[2]  = {(const float*)d_in[8],  (const float*)d_in[16]};
  const float* bet[2]  = {(const float*)d_in[9],  (const float*)d_in[17]};
  float* out = (float*)d_out;

  char* w = (char*)d_ws;
  auto carve = [&](size_t bytes) {
    char* p = w;
    w += (bytes + 255) & ~(size_t)255;
    return p;
  };
  float* xl     = (float*)carve((size_t)NN * DD * 4);
  float* xr     = (float*)carve((size_t)NN * DD * 4);
  int*   deg    = (int*)carve((size_t)NN * 4);
  int*   cur    = (int*)carve((size_t)NN * 4);
  int*   rowp   = (int*)carve((size_t)(NN + 1) * 4);
  int*   colsrc = (int*)carve((size_t)NE * 4);
  int*   bsum   = (int*)carve((size_t)SCAN_B * 4);
  int*   boff   = (int*)carve((size_t)SCAN_B * 4);
  float* hmid   = (float*)carve((size_t)NN * DD * 4);
  unsigned short* wth = (unsigned short*)carve((size_t)256 * 128 * 2);
  unsigned short* wtm = (unsigned short*)carve((size_t)256 * 128 * 2);

  // CSR build (recomputed every call — deterministic, no cross-call state)
  hipMemsetAsync(deg, 0, (size_t)NN * 4, stream);
  hipMemsetAsync(cur, 0, (size_t)NN * 4, stream);
  count_deg<<<(NE + 255) / 256, 256, 0, stream>>>(ei, deg);
  scan_partial<<<SCAN_B, SCAN_T, 0, stream>>>(deg, rowp, bsum);
  scan_bsums<<<1, 128, 0, stream>>>(bsum, boff, rowp);
  scan_add<<<SCAN_B, SCAN_T, 0, stream>>>(rowp, boff);
  scatter_src<<<(NE + 255) / 256, 256, 0, stream>>>(ei, rowp, cur, colsrc);

  for (int l = 0; l < 2; l++) {
    const float* hin = l ? hmid : x;
    float* hout = l ? out : hmid;
    prep_w<<<128, 256, 0, stream>>>(Wl[l], Wr[l], wth, wtm);
    dual_gemm_mfma<<<NN / 16, 256, 0, stream>>>(hin, wth, wtm, bl[l], br[l], xl, xr);
    fused_edge_agg<<<(NN * 64 + 255) / 256, 256, 0, stream>>>(
        rowp, colsrc, xl, xr, att[l], bias[l], gam[l], bet[l], hout);
  }
}

// Round 9
// 333.185 us; speedup vs baseline: 1.3723x; 1.3723x over previous
//
#include <hip/hip_runtime.h>

#define NN 50000
#define NE 600000
#define DD 128
#define NH 4
#define RB_CNT 3125   // NN/16 (exact)
#define RB_PAD 3128   // padded so last GEMM block can load safely

#define SCAN_T 512
#define SCAN_B ((NN + SCAN_T - 1) / SCAN_T)

typedef short s16x8 __attribute__((ext_vector_type(8)));
typedef float f32x4 __attribute__((ext_vector_type(4)));

// fp32 -> bf16 (RNE) and back
__device__ __forceinline__ unsigned short bfh(float f) {
  unsigned u = __float_as_uint(f);
  return (unsigned short)((u + 0x7fffu + ((u >> 16) & 1u)) >> 16);
}
__device__ __forceinline__ float bff(unsigned short h) {
  return __uint_as_float(((unsigned)h) << 16);
}

// ---------- CSR build ----------
__global__ void count_deg(const int* __restrict__ ei, int* __restrict__ deg) {
  int e = blockIdx.x * 256 + threadIdx.x;
  if (e < NE) atomicAdd(deg + ei[NE + e], 1);
}

__global__ __launch_bounds__(SCAN_T) void scan_partial(
    const int* __restrict__ deg, int* __restrict__ rowp, int* __restrict__ bsum) {
  __shared__ int buf[SCAN_T];
  int b = blockIdx.x, t = threadIdx.x;
  int i = b * SCAN_T + t;
  int v = (i < NN) ? deg[i] : 0;
  buf[t] = v;
  __syncthreads();
  for (int o = 1; o < SCAN_T; o <<= 1) {
    int add = (t >= o) ? buf[t - o] : 0;
    __syncthreads();
    buf[t] += add;
    __syncthreads();
  }
  if (i < NN) rowp[i] = buf[t] - v;
  if (t == SCAN_T - 1) bsum[b] = buf[t];
}

__global__ __launch_bounds__(128) void scan_bsums(
    int* __restrict__ bsum, int* __restrict__ boff, int* __restrict__ rowp) {
  __shared__ int buf[128];
  int t = threadIdx.x;
  int v = (t < SCAN_B) ? bsum[t] : 0;
  buf[t] = v;
  __syncthreads();
  for (int o = 1; o < 128; o <<= 1) {
    int add = (t >= o) ? buf[t - o] : 0;
    __syncthreads();
    buf[t] += add;
    __syncthreads();
  }
  if (t < SCAN_B) boff[t] = buf[t] - v;
  if (t == 127) rowp[NN] = buf[t];
}

__global__ __launch_bounds__(SCAN_T) void scan_add(
    int* __restrict__ rowp, const int* __restrict__ boff) {
  int b = blockIdx.x, t = threadIdx.x;
  int i = b * SCAN_T + t;
  if (i < NN) rowp[i] += boff[b];
}

__global__ void scatter_src(const int* __restrict__ ei, const int* __restrict__ rowp,
                            int* __restrict__ cur, int* __restrict__ colsrc) {
  int e = blockIdx.x * 256 + threadIdx.x;
  if (e < NE) {
    int d = ei[NE + e];
    int p = atomicAdd(cur + d, 1);
    colsrc[rowp[d] + p] = ei[e];
  }
}

// ---------- A prep: fp32 -> fragment-major bf16 hi/mid ----------
// layout index: ((rb*4 + kt)*4 + g)*16 + lr, 8 elems each; k(e)=kt*32+(e>>2)*16+4g+(e&3)
__global__ __launch_bounds__(256) void prep_a(
    const float* __restrict__ h, unsigned short* __restrict__ Ah,
    unsigned short* __restrict__ Am) {
  int tid = blockIdx.x * 256 + threadIdx.x;
  if (tid >= RB_CNT * 256) return;
  int lr = tid & 15;
  int g = (tid >> 4) & 3;
  int kt = (tid >> 6) & 3;
  int rb = tid >> 8;
  int row = rb * 16 + lr;
  const float* p = h + (size_t)row * DD + kt * 32 + 4 * g;
  float4 f0 = *(const float4*)(p);
  float4 f1 = *(const float4*)(p + 16);
  float fs[8] = {f0.x, f0.y, f0.z, f0.w, f1.x, f1.y, f1.z, f1.w};
  s16x8 hi, mid;
#pragma unroll
  for (int e = 0; e < 8; e++) {
    unsigned short hh = bfh(fs[e]);
    hi[e] = (short)hh;
    mid[e] = (short)bfh(fs[e] - bff(hh));
  }
  *(s16x8*)(Ah + (size_t)tid * 8) = hi;
  *(s16x8*)(Am + (size_t)tid * 8) = mid;
}

// ---------- W prep: transpose + split, fragment-major ----------
// index: ((ct*4 + kt)*4 + g)*16 + lr ; ct 0..15 (col = ct*16+lr; <128 Wl else Wr)
__global__ __launch_bounds__(256) void prep_w(
    const float* __restrict__ Wl, const float* __restrict__ Wr,
    unsigned short* __restrict__ Bh, unsigned short* __restrict__ Bm) {
  int tid = blockIdx.x * 256 + threadIdx.x;
  if (tid >= 4096) return;
  int lr = tid & 15;
  int g = (tid >> 4) & 3;
  int kt = (tid >> 6) & 3;
  int ct = tid >> 8;
  int col = ct * 16 + lr;
  const float* W = (col < DD) ? Wl : Wr;
  int cc = (col < DD) ? col : col - DD;
  s16x8 hi, mid;
#pragma unroll
  for (int e = 0; e < 8; e++) {
    int k = kt * 32 + ((e >> 2) << 4) + 4 * g + (e & 3);
    float w = W[(size_t)k * DD + cc];
    unsigned short hh = bfh(w);
    hi[e] = (short)hh;
    mid[e] = (short)bfh(w - bff(hh));
  }
  *(s16x8*)(Bh + (size_t)tid * 8) = hi;
  *(s16x8*)(Bm + (size_t)tid * 8) = mid;
}

// ---------- dual GEMM: split-bf16 MFMA, fragment-major coalesced loads ----------
// block: 64 rows x 256 cols, 4 waves; wave: 64x64 (acc[4][4] of 16x16 tiles)
__global__ __launch_bounds__(256, 2) void dual_gemm_mfma(
    const unsigned short* __restrict__ Ah, const unsigned short* __restrict__ Am,
    const unsigned short* __restrict__ Bh, const unsigned short* __restrict__ Bm,
    const float* __restrict__ blv, const float* __restrict__ brv,
    float* __restrict__ xl, float* __restrict__ xr) {
  const int tid = threadIdx.x;
  const int lane = tid & 63;
  const int wv = tid >> 6;
  const int lr = lane & 15;
  const int g = lane >> 4;
  const int rb0 = blockIdx.x * 4;

  f32x4 acc[4][4];
#pragma unroll
  for (int rt = 0; rt < 4; rt++)
#pragma unroll
    for (int nt = 0; nt < 4; nt++)
#pragma unroll
      for (int e = 0; e < 4; e++) acc[rt][nt][e] = 0.f;

#pragma unroll
  for (int kt = 0; kt < 4; kt++) {
    s16x8 ah[4], am[4], bh[4], bm[4];
#pragma unroll
    for (int rt = 0; rt < 4; rt++) {
      size_t off = ((((size_t)((rb0 + rt) * 4 + kt)) * 4 + g) * 16 + lr) * 8;
      ah[rt] = *(const s16x8*)(Ah + off);
      am[rt] = *(const s16x8*)(Am + off);
    }
#pragma unroll
    for (int nt = 0; nt < 4; nt++) {
      int ct = wv * 4 + nt;
      size_t off = ((((size_t)(ct * 4 + kt)) * 4 + g) * 16 + lr) * 8;
      bh[nt] = *(const s16x8*)(Bh + off);
      bm[nt] = *(const s16x8*)(Bm + off);
    }
#pragma unroll
    for (int rt = 0; rt < 4; rt++)
#pragma unroll
      for (int nt = 0; nt < 4; nt++) {
        acc[rt][nt] = __builtin_amdgcn_mfma_f32_16x16x32_bf16(ah[rt], bh[nt], acc[rt][nt], 0, 0, 0);
        acc[rt][nt] = __builtin_amdgcn_mfma_f32_16x16x32_bf16(ah[rt], bm[nt], acc[rt][nt], 0, 0, 0);
        acc[rt][nt] = __builtin_amdgcn_mfma_f32_16x16x32_bf16(am[rt], bh[nt], acc[rt][nt], 0, 0, 0);
      }
  }

  // epilogue: C row=(lane>>4)*4+reg within tile, col=lane&15 (m89 mapping)
#pragma unroll
  for (int nt = 0; nt < 4; nt++) {
    int col = wv * 64 + nt * 16 + lr;
    float bv = (col < DD) ? blv[col] : brv[col - DD];
    float* dst = (col < DD) ? (xl + col) : (xr + (col - DD));
#pragma unroll
    for (int rt = 0; rt < 4; rt++) {
      int rowb = blockIdx.x * 64 + rt * 16 + 4 * g;
#pragma unroll
      for (int r = 0; r < 4; r++)
        if (rowb + r < NN) dst[(size_t)(rowb + r) * DD] = acc[rt][nt][r] + bv;
    }
  }
}

// ---------- fused edge path, chunk-4 online softmax ----------
// SPLIT=1: write fragment-major bf16 hi/mid (next layer's A); SPLIT=0: write fp32 out.
template <int SPLIT>
__global__ __launch_bounds__(256) void fused_edge_agg(
    const int* __restrict__ rowp, const int* __restrict__ colsrc,
    const float* __restrict__ xl, const float* __restrict__ xr,
    const float* __restrict__ att, const float* __restrict__ bias,
    const float* __restrict__ gam, const float* __restrict__ bet,
    float* __restrict__ out, unsigned short* __restrict__ Oh,
    unsigned short* __restrict__ Om) {
  int node = (blockIdx.x * 256 + threadIdx.x) >> 6;
  if (node >= NN) return;
  int lane = threadIdx.x & 63;
  int c = lane << 1;                 // dims c, c+1 (head = lane>>4)
  float2 xrv = *(const float2*)(xr + (size_t)node * DD + c);
  float2 atv = *(const float2*)(att + c);
  int j0 = rowp[node], j1 = rowp[node + 1];

  float m = -INFINITY, den = 0.f, ax = 0.f, ay = 0.f;

  for (int j = j0; j < j1; j += 4) {
    int n = j1 - j; if (n > 4) n = 4;
    float2 xv[4];
    float p[4];
#pragma unroll
    for (int k = 0; k < 4; k++) { xv[k] = make_float2(0.f, 0.f); p[k] = -INFINITY; }
#pragma unroll
    for (int k = 0; k < 4; k++) {
      if (k < n) {
        int s = colsrc[j + k];
        xv[k] = *(const float2*)(xl + (size_t)s * DD + c);
      }
    }
#pragma unroll
    for (int k = 0; k < 4; k++) {
      if (k < n) {
        float vx = xv[k].x + xrv.x, vy = xv[k].y + xrv.y;
        vx = vx > 0.f ? vx : 0.2f * vx;      // leaky_relu NEG=0.2
        vy = vy > 0.f ? vy : 0.2f * vy;
        float pp = vx * atv.x + vy * atv.y;
        pp += __shfl_xor(pp, 1);
        pp += __shfl_xor(pp, 2);
        pp += __shfl_xor(pp, 4);
        pp += __shfl_xor(pp, 8);             // per-head (16-lane) total
        p[k] = pp;
      }
    }
    float m4 = fmaxf(fmaxf(p[0], p[1]), fmaxf(p[2], p[3]));
    float w0 = __expf(p[0] - m4), w1 = __expf(p[1] - m4);
    float w2 = __expf(p[2] - m4), w3 = __expf(p[3] - m4);
    float sw = (w0 + w1) + (w2 + w3);
    float sx = (w0 * xv[0].x + w1 * xv[1].x) + (w2 * xv[2].x + w3 * xv[3].x);
    float sy = (w0 * xv[0].y + w1 * xv[1].y) + (w2 * xv[2].y + w3 * xv[3].y);
    float mn = fmaxf(m, m4);
    float a = __expf(m - mn);
    float b = __expf(m4 - mn);
    den = den * a + sw * b;
    ax  = ax * a + sx * b;
    ay  = ay * a + sy * b;
    m = mn;
  }

  float inv = 1.f / (den + 1e-16f);
  float vx = ax * inv + bias[c];
  float vy = ay * inv + bias[c + 1];
  float s1 = vx + vy, s2 = vx * vx + vy * vy;
#pragma unroll
  for (int o = 1; o < 64; o <<= 1) { s1 += __shfl_xor(s1, o); s2 += __shfl_xor(s2, o); }
  float mean = s1 * (1.f / 128.f);
  float var = s2 * (1.f / 128.f) - mean * mean;
  float rstd = rsqrtf(var + 1e-5f);
  float nx = (vx - mean) * rstd * gam[c] + bet[c];
  float ny = (vy - mean) * rstd * gam[c + 1] + bet[c + 1];
  nx = nx > 0.f ? nx : expf(nx) - 1.f;       // ELU
  ny = ny > 0.f ? ny : expf(ny) - 1.f;

  if (SPLIT) {
    // fragment-major split write: k==c maps to (kt,g,e)
    int rb = node >> 4, lr16 = node & 15;
    int kt = c >> 5, rem = c & 31;
    int g = (rem & 15) >> 2;
    int e = ((rem >> 4) << 2) | (rem & 3);
    size_t off = ((((size_t)(rb * 4 + kt)) * 4 + g) * 16 + lr16) * 8 + e;
    unsigned short hx = bfh(nx), hy = bfh(ny);
    ushort2 hv; hv.x = hx; hv.y = hy;
    ushort2 mv; mv.x = bfh(nx - bff(hx)); mv.y = bfh(ny - bff(hy));
    *(ushort2*)(Oh + off) = hv;
    *(ushort2*)(Om + off) = mv;
  } else {
    out[(size_t)node * DD + c]     = nx;
    out[(size_t)node * DD + c + 1] = ny;
  }
}

extern "C" void kernel_launch(void* const* d_in, const int* in_sizes, int n_in,
                              void* d_out, int out_size, void* d_ws, size_t ws_size,
                              hipStream_t stream) {
  const float* x  = (const float*)d_in[0];
  const int*   ei = (const int*)d_in[1];
  const float* Wl[2]   = {(const float*)d_in[2],  (const float*)d_in[10]};
  const float* bl[2]   = {(const float*)d_in[3],  (const float*)d_in[11]};
  const float* Wr[2]   = {(const float*)d_in[4],  (const float*)d_in[12]};
  const float* br[2]   = {(const float*)d_in[5],  (const float*)d_in[13]};
  const float* att[2]  = {(const float*)d_in[6],  (const float*)d_in[14]};
  const float* bias[2] = {(const float*)d_in[7],  (const float*)d_in[15]};
  const float* gam[2]  = {(const float*)d_in[8],  (const float*)d_in[16]};
  const float* bet[2]  = {(const float*)d_in[9],  (const float*)d_in[17]};
  float* out = (float*)d_out;

  char* w = (char*)d_ws;
  auto carve = [&](size_t bytes) {
    char* p = w;
    w += (bytes + 255) & ~(size_t)255;
    return p;
  };
  float* xl     = (float*)carve((size_t)NN * DD * 4);
  float* xr     = (float*)carve((size_t)NN * DD * 4);
  int*   deg    = (int*)carve((size_t)NN * 4);
  int*   cur    = (int*)carve((size_t)NN * 4);
  int*   rowp   = (int*)carve((size_t)(NN + 1) * 4);
  int*   colsrc = (int*)carve((size_t)NE * 4);
  int*   bsum   = (int*)carve((size_t)SCAN_B * 4);
  int*   boff   = (int*)carve((size_t)SCAN_B * 4);
  unsigned short* Ah = (unsigned short*)carve((size_t)RB_PAD * 2048 * 2);
  unsigned short* Am = (unsigned short*)carve((size_t)RB_PAD * 2048 * 2);
  unsigned short* Bh = (unsigned short*)carve((size_t)4096 * 8 * 2);
  unsigned short* Bm = (unsigned short*)carve((size_t)4096 * 8 * 2);

  // CSR build (recomputed every call — deterministic, no cross-call state)
  hipMemsetAsync(deg, 0, (size_t)NN * 4, stream);
  hipMemsetAsync(cur, 0, (size_t)NN * 4, stream);
  count_deg<<<(NE + 255) / 256, 256, 0, stream>>>(ei, deg);
  scan_partial<<<SCAN_B, SCAN_T, 0, stream>>>(deg, rowp, bsum);
  scan_bsums<<<1, 128, 0, stream>>>(bsum, boff, rowp);
  scan_add<<<SCAN_B, SCAN_T, 0, stream>>>(rowp, boff);
  scatter_src<<<(NE + 255) / 256, 256, 0, stream>>>(ei, rowp, cur, colsrc);

  // layer-0 input split (layer-1's split is produced by fused_edge_agg<1>)
  prep_a<<<RB_CNT, 256, 0, stream>>>(x, Ah, Am);

  for (int l = 0; l < 2; l++) {
    prep_w<<<16, 256, 0, stream>>>(Wl[l], Wr[l], Bh, Bm);
    dual_gemm_mfma<<<(NN + 63) / 64, 256, 0, stream>>>(Ah, Am, Bh, Bm, bl[l], br[l], xl, xr);
    if (l == 0) {
      fused_edge_agg<1><<<(NN * 64 + 255) / 256, 256, 0, stream>>>(
          rowp, colsrc, xl, xr, att[l], bias[l], gam[l], bet[l], out, Ah, Am);
    } else {
      fused_edge_agg<0><<<(NN * 64 + 255) / 256, 256, 0, stream>>>(
          rowp, colsrc, xl, xr, att[l], bias[l], gam[l], bet[l], out, Ah, Am);
    }
  }
}

// Round 10
// 272.849 us; speedup vs baseline: 1.6758x; 1.2211x over previous
//
#include <hip/hip_runtime.h>

#define NN 50000
#define NE 600000
#define DD 128
#define NH 4
#define RB_CNT 3125   // NN/16 (exact)
#define RB_PAD 3128   // padded so last GEMM block can load safely

#define SCAN_T 512
#define SCAN_B ((NN + SCAN_T - 1) / SCAN_T)

#define LOG2E 1.44269504088896340736f

typedef short s16x8 __attribute__((ext_vector_type(8)));
typedef float f32x4 __attribute__((ext_vector_type(4)));

// fp32 -> bf16 (RNE) and back
__device__ __forceinline__ unsigned short bfh(float f) {
  unsigned u = __float_as_uint(f);
  return (unsigned short)((u + 0x7fffu + ((u >> 16) & 1u)) >> 16);
}
__device__ __forceinline__ float bff(unsigned short h) {
  return __uint_as_float(((unsigned)h) << 16);
}

// cross-lane add via DPP (full-rate VALU, no LDS). CTRL: 0xB1 xor1, 0x4E xor2,
// 0x124 row_ror:4, 0x128 row_ror:8 (rotate-reduce valid for commutative add).
template <int CTRL>
__device__ __forceinline__ float dpp_add(float x) {
  int y = __builtin_amdgcn_update_dpp(0, __float_as_int(x), CTRL, 0xf, 0xf, true);
  return x + __int_as_float(y);
}

// ---------- CSR build ----------
__global__ void count_deg(const int* __restrict__ ei, int* __restrict__ deg) {
  int e = blockIdx.x * 256 + threadIdx.x;
  if (e < NE) atomicAdd(deg + ei[NE + e], 1);
}

__global__ __launch_bounds__(SCAN_T) void scan_partial(
    const int* __restrict__ deg, int* __restrict__ rowp, int* __restrict__ bsum) {
  __shared__ int buf[SCAN_T];
  int b = blockIdx.x, t = threadIdx.x;
  int i = b * SCAN_T + t;
  int v = (i < NN) ? deg[i] : 0;
  buf[t] = v;
  __syncthreads();
  for (int o = 1; o < SCAN_T; o <<= 1) {
    int add = (t >= o) ? buf[t - o] : 0;
    __syncthreads();
    buf[t] += add;
    __syncthreads();
  }
  if (i < NN) rowp[i] = buf[t] - v;
  if (t == SCAN_T - 1) bsum[b] = buf[t];
}

__global__ __launch_bounds__(128) void scan_bsums(
    int* __restrict__ bsum, int* __restrict__ boff, int* __restrict__ rowp) {
  __shared__ int buf[128];
  int t = threadIdx.x;
  int v = (t < SCAN_B) ? bsum[t] : 0;
  buf[t] = v;
  __syncthreads();
  for (int o = 1; o < 128; o <<= 1) {
    int add = (t >= o) ? buf[t - o] : 0;
    __syncthreads();
    buf[t] += add;
    __syncthreads();
  }
  if (t < SCAN_B) boff[t] = buf[t] - v;
  if (t == 127) rowp[NN] = buf[t];
}

__global__ __launch_bounds__(SCAN_T) void scan_add(
    int* __restrict__ rowp, const int* __restrict__ boff) {
  int b = blockIdx.x, t = threadIdx.x;
  int i = b * SCAN_T + t;
  if (i < NN) rowp[i] += boff[b];
}

__global__ void scatter_src(const int* __restrict__ ei, const int* __restrict__ rowp,
                            int* __restrict__ cur, int* __restrict__ colsrc) {
  int e = blockIdx.x * 256 + threadIdx.x;
  if (e < NE) {
    int d = ei[NE + e];
    int p = atomicAdd(cur + d, 1);
    colsrc[rowp[d] + p] = ei[e];
  }
}

// ---------- A prep: fp32 -> fragment-major bf16 hi/mid ----------
__global__ __launch_bounds__(256) void prep_a(
    const float* __restrict__ h, unsigned short* __restrict__ Ah,
    unsigned short* __restrict__ Am) {
  int tid = blockIdx.x * 256 + threadIdx.x;
  if (tid >= RB_CNT * 256) return;
  int lr = tid & 15;
  int g = (tid >> 4) & 3;
  int kt = (tid >> 6) & 3;
  int rb = tid >> 8;
  int row = rb * 16 + lr;
  const float* p = h + (size_t)row * DD + kt * 32 + 4 * g;
  float4 f0 = *(const float4*)(p);
  float4 f1 = *(const float4*)(p + 16);
  float fs[8] = {f0.x, f0.y, f0.z, f0.w, f1.x, f1.y, f1.z, f1.w};
  s16x8 hi, mid;
#pragma unroll
  for (int e = 0; e < 8; e++) {
    unsigned short hh = bfh(fs[e]);
    hi[e] = (short)hh;
    mid[e] = (short)bfh(fs[e] - bff(hh));
  }
  *(s16x8*)(Ah + (size_t)tid * 8) = hi;
  *(s16x8*)(Am + (size_t)tid * 8) = mid;
}

// ---------- W prep: transpose + split, fragment-major ----------
__global__ __launch_bounds__(256) void prep_w(
    const float* __restrict__ Wl, const float* __restrict__ Wr,
    unsigned short* __restrict__ Bh, unsigned short* __restrict__ Bm) {
  int tid = blockIdx.x * 256 + threadIdx.x;
  if (tid >= 4096) return;
  int lr = tid & 15;
  int g = (tid >> 4) & 3;
  int kt = (tid >> 6) & 3;
  int ct = tid >> 8;
  int col = ct * 16 + lr;
  const float* W = (col < DD) ? Wl : Wr;
  int cc = (col < DD) ? col : col - DD;
  s16x8 hi, mid;
#pragma unroll
  for (int e = 0; e < 8; e++) {
    int k = kt * 32 + ((e >> 2) << 4) + 4 * g + (e & 3);
    float w = W[(size_t)k * DD + cc];
    unsigned short hh = bfh(w);
    hi[e] = (short)hh;
    mid[e] = (short)bfh(w - bff(hh));
  }
  *(s16x8*)(Bh + (size_t)tid * 8) = hi;
  *(s16x8*)(Bm + (size_t)tid * 8) = mid;
}

// ---------- dual GEMM: split-bf16 MFMA, fragment-major coalesced loads ----------
__global__ __launch_bounds__(256, 2) void dual_gemm_mfma(
    const unsigned short* __restrict__ Ah, const unsigned short* __restrict__ Am,
    const unsigned short* __restrict__ Bh, const unsigned short* __restrict__ Bm,
    const float* __restrict__ blv, const float* __restrict__ brv,
    float* __restrict__ xl, float* __restrict__ xr) {
  const int tid = threadIdx.x;
  const int lane = tid & 63;
  const int wv = tid >> 6;
  const int lr = lane & 15;
  const int g = lane >> 4;
  const int rb0 = blockIdx.x * 4;

  f32x4 acc[4][4];
#pragma unroll
  for (int rt = 0; rt < 4; rt++)
#pragma unroll
    for (int nt = 0; nt < 4; nt++)
#pragma unroll
      for (int e = 0; e < 4; e++) acc[rt][nt][e] = 0.f;

#pragma unroll
  for (int kt = 0; kt < 4; kt++) {
    s16x8 ah[4], am[4], bh[4], bm[4];
#pragma unroll
    for (int rt = 0; rt < 4; rt++) {
      size_t off = ((((size_t)((rb0 + rt) * 4 + kt)) * 4 + g) * 16 + lr) * 8;
      ah[rt] = *(const s16x8*)(Ah + off);
      am[rt] = *(const s16x8*)(Am + off);
    }
#pragma unroll
    for (int nt = 0; nt < 4; nt++) {
      int ct = wv * 4 + nt;
      size_t off = ((((size_t)(ct * 4 + kt)) * 4 + g) * 16 + lr) * 8;
      bh[nt] = *(const s16x8*)(Bh + off);
      bm[nt] = *(const s16x8*)(Bm + off);
    }
#pragma unroll
    for (int rt = 0; rt < 4; rt++)
#pragma unroll
      for (int nt = 0; nt < 4; nt++) {
        acc[rt][nt] = __builtin_amdgcn_mfma_f32_16x16x32_bf16(ah[rt], bh[nt], acc[rt][nt], 0, 0, 0);
        acc[rt][nt] = __builtin_amdgcn_mfma_f32_16x16x32_bf16(ah[rt], bm[nt], acc[rt][nt], 0, 0, 0);
        acc[rt][nt] = __builtin_amdgcn_mfma_f32_16x16x32_bf16(am[rt], bh[nt], acc[rt][nt], 0, 0, 0);
      }
  }

#pragma unroll
  for (int nt = 0; nt < 4; nt++) {
    int col = wv * 64 + nt * 16 + lr;
    float bv = (col < DD) ? blv[col] : brv[col - DD];
    float* dst = (col < DD) ? (xl + col) : (xr + (col - DD));
#pragma unroll
    for (int rt = 0; rt < 4; rt++) {
      int rowb = blockIdx.x * 64 + rt * 16 + 4 * g;
#pragma unroll
      for (int r = 0; r < 4; r++)
        if (rowb + r < NN) dst[(size_t)(rowb + r) * DD] = acc[rt][nt][r] + bv;
    }
  }
}

// ---------- fused edge path: DPP reduce, scalarized gathers, chunk-4 ----------
template <int SPLIT>
__global__ __launch_bounds__(256) void fused_edge_agg(
    const int* __restrict__ rowp, const int* __restrict__ colsrc,
    const float* __restrict__ xl, const float* __restrict__ xr,
    const float* __restrict__ att, const float* __restrict__ bias,
    const float* __restrict__ gam, const float* __restrict__ bet,
    float* __restrict__ out, unsigned short* __restrict__ Oh,
    unsigned short* __restrict__ Om) {
  int node = __builtin_amdgcn_readfirstlane((blockIdx.x * 256 + threadIdx.x) >> 6);
  if (node >= NN) return;
  int lane = threadIdx.x & 63;
  int c = lane << 1;                 // dims c, c+1 (head = lane>>4)
  float2 xrv = *(const float2*)(xr + (size_t)node * DD + c);
  float2 atv = *(const float2*)(att + c);
  int j0 = __builtin_amdgcn_readfirstlane(rowp[node]);
  int j1 = __builtin_amdgcn_readfirstlane(rowp[node + 1]);

  // m, den in exp2 domain (scores pre-scaled by log2e)
  float m = -INFINITY, den = 0.f, ax = 0.f, ay = 0.f;

  for (int j = j0; j < j1; j += 4) {
    int n = j1 - j; if (n > 4) n = 4;
    float2 xv[4];
    float p[4];
#pragma unroll
    for (int k = 0; k < 4; k++) { xv[k] = make_float2(0.f, 0.f); p[k] = -INFINITY; }
#pragma unroll
    for (int k = 0; k < 4; k++) {
      if (k < n) {
        int s = __builtin_amdgcn_readfirstlane(colsrc[j + k]);
        xv[k] = *(const float2*)(xl + (size_t)s * DD + c);
      }
    }
#pragma unroll
    for (int k = 0; k < 4; k++) {
      if (k < n) {
        float vx = xv[k].x + xrv.x, vy = xv[k].y + xrv.y;
        vx = fmaxf(vx, 0.2f * vx);           // leaky_relu NEG=0.2 (2 ops)
        vy = fmaxf(vy, 0.2f * vy);
        float pp = vx * atv.x + vy * atv.y;
        // 16-lane head reduce: 4x v_add_f32 with DPP (no LDS, no waits)
        pp = dpp_add<0xB1>(pp);              // xor 1 (quad_perm 1,0,3,2)
        pp = dpp_add<0x4E>(pp);              // xor 2 (quad_perm 2,3,0,1)
        pp = dpp_add<0x124>(pp);             // row_ror:4
        pp = dpp_add<0x128>(pp);             // row_ror:8
        p[k] = pp * LOG2E;                   // exp2 domain
      }
    }
    float m4 = fmaxf(fmaxf(p[0], p[1]), fmaxf(p[2], p[3]));
    float w0 = exp2f(p[0] - m4), w1 = exp2f(p[1] - m4);
    float w2 = exp2f(p[2] - m4), w3 = exp2f(p[3] - m4);
    float sw = (w0 + w1) + (w2 + w3);
    float sx = (w0 * xv[0].x + w1 * xv[1].x) + (w2 * xv[2].x + w3 * xv[3].x);
    float sy = (w0 * xv[0].y + w1 * xv[1].y) + (w2 * xv[2].y + w3 * xv[3].y);
    float mn = fmaxf(m, m4);
    float a = exp2f(m - mn);
    float b = exp2f(m4 - mn);
    den = den * a + sw * b;
    ax  = ax * a + sx * b;
    ay  = ay * a + sy * b;
    m = mn;
  }

  float inv = 1.f / (den + 1e-16f);
  float vx = ax * inv + bias[c];
  float vy = ay * inv + bias[c + 1];
  float s1 = vx + vy, s2 = vx * vx + vy * vy;
  s1 = dpp_add<0xB1>(s1); s2 = dpp_add<0xB1>(s2);
  s1 = dpp_add<0x4E>(s1); s2 = dpp_add<0x4E>(s2);
  s1 = dpp_add<0x124>(s1); s2 = dpp_add<0x124>(s2);
  s1 = dpp_add<0x128>(s1); s2 = dpp_add<0x128>(s2);
  s1 += __shfl_xor(s1, 16); s2 += __shfl_xor(s2, 16);
  s1 += __shfl_xor(s1, 32); s2 += __shfl_xor(s2, 32);
  float mean = s1 * (1.f / 128.f);
  float var = s2 * (1.f / 128.f) - mean * mean;
  float rstd = rsqrtf(var + 1e-5f);
  float nx = (vx - mean) * rstd * gam[c] + bet[c];
  float ny = (vy - mean) * rstd * gam[c + 1] + bet[c + 1];
  nx = nx > 0.f ? nx : expf(nx) - 1.f;       // ELU
  ny = ny > 0.f ? ny : expf(ny) - 1.f;

  if (SPLIT) {
    int rb = node >> 4, lr16 = node & 15;
    int kt = c >> 5, rem = c & 31;
    int g = (rem & 15) >> 2;
    int e = ((rem >> 4) << 2) | (rem & 3);
    size_t off = ((((size_t)(rb * 4 + kt)) * 4 + g) * 16 + lr16) * 8 + e;
    unsigned short hx = bfh(nx), hy = bfh(ny);
    ushort2 hv; hv.x = hx; hv.y = hy;
    ushort2 mv; mv.x = bfh(nx - bff(hx)); mv.y = bfh(ny - bff(hy));
    *(ushort2*)(Oh + off) = hv;
    *(ushort2*)(Om + off) = mv;
  } else {
    out[(size_t)node * DD + c]     = nx;
    out[(size_t)node * DD + c + 1] = ny;
  }
}

extern "C" void kernel_launch(void* const* d_in, const int* in_sizes, int n_in,
                              void* d_out, int out_size, void* d_ws, size_t ws_size,
                              hipStream_t stream) {
  const float* x  = (const float*)d_in[0];
  const int*   ei = (const int*)d_in[1];
  const float* Wl[2]   = {(const float*)d_in[2],  (const float*)d_in[10]};
  const float* bl[2]   = {(const float*)d_in[3],  (const float*)d_in[11]};
  const float* Wr[2]   = {(const float*)d_in[4],  (const float*)d_in[12]};
  const float* br[2]   = {(const float*)d_in[5],  (const float*)d_in[13]};
  const float* att[2]  = {(const float*)d_in[6],  (const float*)d_in[14]};
  const float* bias[2] = {(const float*)d_in[7],  (const float*)d_in[15]};
  const float* gam[2]  = {(const float*)d_in[8],  (const float*)d_in[16]};
  const float* bet[2]  = {(const float*)d_in[9],  (const float*)d_in[17]};
  float* out = (float*)d_out;

  char* w = (char*)d_ws;
  auto carve = [&](size_t bytes) {
    char* p = w;
    w += (bytes + 255) & ~(size_t)255;
    return p;
  };
  float* xl     = (float*)carve((size_t)NN * DD * 4);
  float* xr     = (float*)carve((size_t)NN * DD * 4);
  int*   deg    = (int*)carve((size_t)NN * 4);
  int*   cur    = (int*)carve((size_t)NN * 4);
  int*   rowp   = (int*)carve((size_t)(NN + 1) * 4);
  int*   colsrc = (int*)carve((size_t)NE * 4);
  int*   bsum   = (int*)carve((size_t)SCAN_B * 4);
  int*   boff   = (int*)carve((size_t)SCAN_B * 4);
  unsigned short* Ah = (unsigned short*)carve((size_t)RB_PAD * 2048 * 2);
  unsigned short* Am = (unsigned short*)carve((size_t)RB_PAD * 2048 * 2);
  unsigned short* Bh = (unsigned short*)carve((size_t)4096 * 8 * 2);
  unsigned short* Bm = (unsigned short*)carve((size_t)4096 * 8 * 2);

  // CSR build (recomputed every call — deterministic, no cross-call state)
  hipMemsetAsync(deg, 0, (size_t)NN * 4, stream);
  hipMemsetAsync(cur, 0, (size_t)NN * 4, stream);
  count_deg<<<(NE + 255) / 256, 256, 0, stream>>>(ei, deg);
  scan_partial<<<SCAN_B, SCAN_T, 0, stream>>>(deg, rowp, bsum);
  scan_bsums<<<1, 128, 0, stream>>>(bsum, boff, rowp);
  scan_add<<<SCAN_B, SCAN_T, 0, stream>>>(rowp, boff);
  scatter_src<<<(NE + 255) / 256, 256, 0, stream>>>(ei, rowp, cur, colsrc);

  // layer-0 input split (layer-1's split is produced by fused_edge_agg<1>)
  prep_a<<<RB_CNT, 256, 0, stream>>>(x, Ah, Am);

  for (int l = 0; l < 2; l++) {
    prep_w<<<16, 256, 0, stream>>>(Wl[l], Wr[l], Bh, Bm);
    dual_gemm_mfma<<<(NN + 63) / 64, 256, 0, stream>>>(Ah, Am, Bh, Bm, bl[l], br[l], xl, xr);
    if (l == 0) {
      fused_edge_agg<1><<<(NN * 64 + 255) / 256, 256, 0, stream>>>(
          rowp, colsrc, xl, xr, att[l], bias[l], gam[l], bet[l], out, Ah, Am);
    } else {
      fused_edge_agg<0><<<(NN * 64 + 255) / 256, 256, 0, stream>>>(
          rowp, colsrc, xl, xr, att[l], bias[l], gam[l], bet[l], out, Ah, Am);
    }
  }
}

// Round 11
// 268.217 us; speedup vs baseline: 1.7047x; 1.0173x over previous
//
#include <hip/hip_runtime.h>

#define NN 50000
#define NE 600000
#define DD 128
#define NH 4
#define RB_CNT 3125   // NN/16 (exact)
#define RB_PAD 3128

#define SCAN_T 512
#define SCAN_B ((NN + SCAN_T - 1) / SCAN_T)

#define LOG2E 1.44269504088896340736f

typedef short s16x8 __attribute__((ext_vector_type(8)));
typedef float f32x4 __attribute__((ext_vector_type(4)));

// fp32 -> bf16 (RNE) and back
__device__ __forceinline__ unsigned short bfh(float f) {
  unsigned u = __float_as_uint(f);
  return (unsigned short)((u + 0x7fffu + ((u >> 16) & 1u)) >> 16);
}
__device__ __forceinline__ float bff(unsigned short h) {
  return __uint_as_float(((unsigned)h) << 16);
}

// cross-lane add via DPP. 0xB1 quad xor1, 0x4E quad xor2, 0x141 row_half_mirror
// (8-lane group sum after xor1+xor2), 0x124/0x128 row_ror:4/:8.
template <int CTRL>
__device__ __forceinline__ float dpp_add(float x) {
  int y = __builtin_amdgcn_update_dpp(0, __float_as_int(x), CTRL, 0xf, 0xf, true);
  return x + __int_as_float(y);
}

// ---------- CSR build ----------
__global__ void count_deg(const int* __restrict__ ei, int* __restrict__ deg) {
  int e = blockIdx.x * 256 + threadIdx.x;
  if (e < NE) atomicAdd(deg + ei[NE + e], 1);
}

__global__ __launch_bounds__(SCAN_T) void scan_partial(
    const int* __restrict__ deg, int* __restrict__ rowp, int* __restrict__ bsum) {
  __shared__ int buf[SCAN_T];
  int b = blockIdx.x, t = threadIdx.x;
  int i = b * SCAN_T + t;
  int v = (i < NN) ? deg[i] : 0;
  buf[t] = v;
  __syncthreads();
  for (int o = 1; o < SCAN_T; o <<= 1) {
    int add = (t >= o) ? buf[t - o] : 0;
    __syncthreads();
    buf[t] += add;
    __syncthreads();
  }
  if (i < NN) rowp[i] = buf[t] - v;
  if (t == SCAN_T - 1) bsum[b] = buf[t];
}

__global__ __launch_bounds__(128) void scan_bsums(
    int* __restrict__ bsum, int* __restrict__ boff, int* __restrict__ rowp) {
  __shared__ int buf[128];
  int t = threadIdx.x;
  int v = (t < SCAN_B) ? bsum[t] : 0;
  buf[t] = v;
  __syncthreads();
  for (int o = 1; o < 128; o <<= 1) {
    int add = (t >= o) ? buf[t - o] : 0;
    __syncthreads();
    buf[t] += add;
    __syncthreads();
  }
  if (t < SCAN_B) boff[t] = buf[t] - v;
  if (t == 127) rowp[NN] = buf[t];
}

__global__ __launch_bounds__(SCAN_T) void scan_add(
    int* __restrict__ rowp, const int* __restrict__ boff) {
  int b = blockIdx.x, t = threadIdx.x;
  int i = b * SCAN_T + t;
  if (i < NN) rowp[i] += boff[b];
}

// store src * 256 (bf16 row byte-stride) — saves a shift on every gather
__global__ void scatter_src(const int* __restrict__ ei, const int* __restrict__ rowp,
                            int* __restrict__ cur, int* __restrict__ colsrc) {
  int e = blockIdx.x * 256 + threadIdx.x;
  if (e < NE) {
    int d = ei[NE + e];
    int p = atomicAdd(cur + d, 1);
    colsrc[rowp[d] + p] = ei[e] << 8;
  }
}

// ---------- A prep: fp32 -> fragment-major bf16 hi/mid ----------
__global__ __launch_bounds__(256) void prep_a(
    const float* __restrict__ h, unsigned short* __restrict__ Ah,
    unsigned short* __restrict__ Am) {
  int tid = blockIdx.x * 256 + threadIdx.x;
  if (tid >= RB_CNT * 256) return;
  int lr = tid & 15;
  int g = (tid >> 4) & 3;
  int kt = (tid >> 6) & 3;
  int rb = tid >> 8;
  int row = rb * 16 + lr;
  const float* p = h + (size_t)row * DD + kt * 32 + 4 * g;
  float4 f0 = *(const float4*)(p);
  float4 f1 = *(const float4*)(p + 16);
  float fs[8] = {f0.x, f0.y, f0.z, f0.w, f1.x, f1.y, f1.z, f1.w};
  s16x8 hi, mid;
#pragma unroll
  for (int e = 0; e < 8; e++) {
    unsigned short hh = bfh(fs[e]);
    hi[e] = (short)hh;
    mid[e] = (short)bfh(fs[e] - bff(hh));
  }
  *(s16x8*)(Ah + (size_t)tid * 8) = hi;
  *(s16x8*)(Am + (size_t)tid * 8) = mid;
}

// ---------- W prep: transpose + split, fragment-major ----------
__global__ __launch_bounds__(256) void prep_w(
    const float* __restrict__ Wl, const float* __restrict__ Wr,
    unsigned short* __restrict__ Bh, unsigned short* __restrict__ Bm) {
  int tid = blockIdx.x * 256 + threadIdx.x;
  if (tid >= 4096) return;
  int lr = tid & 15;
  int g = (tid >> 4) & 3;
  int kt = (tid >> 6) & 3;
  int ct = tid >> 8;
  int col = ct * 16 + lr;
  const float* W = (col < DD) ? Wl : Wr;
  int cc = (col < DD) ? col : col - DD;
  s16x8 hi, mid;
#pragma unroll
  for (int e = 0; e < 8; e++) {
    int k = kt * 32 + ((e >> 2) << 4) + 4 * g + (e & 3);
    float w = W[(size_t)k * DD + cc];
    unsigned short hh = bfh(w);
    hi[e] = (short)hh;
    mid[e] = (short)bfh(w - bff(hh));
  }
  *(s16x8*)(Bh + (size_t)tid * 8) = hi;
  *(s16x8*)(Bm + (size_t)tid * 8) = mid;
}

// ---------- dual GEMM: split-bf16 MFMA; xl written as bf16, xr as fp32 ----------
__global__ __launch_bounds__(256, 2) void dual_gemm_mfma(
    const unsigned short* __restrict__ Ah, const unsigned short* __restrict__ Am,
    const unsigned short* __restrict__ Bh, const unsigned short* __restrict__ Bm,
    const float* __restrict__ blv, const float* __restrict__ brv,
    unsigned short* __restrict__ xlb, float* __restrict__ xr) {
  const int tid = threadIdx.x;
  const int lane = tid & 63;
  const int wv = tid >> 6;
  const int lr = lane & 15;
  const int g = lane >> 4;
  const int rb0 = blockIdx.x * 4;

  f32x4 acc[4][4];
#pragma unroll
  for (int rt = 0; rt < 4; rt++)
#pragma unroll
    for (int nt = 0; nt < 4; nt++)
#pragma unroll
      for (int e = 0; e < 4; e++) acc[rt][nt][e] = 0.f;

#pragma unroll
  for (int kt = 0; kt < 4; kt++) {
    s16x8 ah[4], am[4], bh[4], bm[4];
#pragma unroll
    for (int rt = 0; rt < 4; rt++) {
      size_t off = ((((size_t)((rb0 + rt) * 4 + kt)) * 4 + g) * 16 + lr) * 8;
      ah[rt] = *(const s16x8*)(Ah + off);
      am[rt] = *(const s16x8*)(Am + off);
    }
#pragma unroll
    for (int nt = 0; nt < 4; nt++) {
      int ct = wv * 4 + nt;
      size_t off = ((((size_t)(ct * 4 + kt)) * 4 + g) * 16 + lr) * 8;
      bh[nt] = *(const s16x8*)(Bh + off);
      bm[nt] = *(const s16x8*)(Bm + off);
    }
#pragma unroll
    for (int rt = 0; rt < 4; rt++)
#pragma unroll
      for (int nt = 0; nt < 4; nt++) {
        acc[rt][nt] = __builtin_amdgcn_mfma_f32_16x16x32_bf16(ah[rt], bh[nt], acc[rt][nt], 0, 0, 0);
        acc[rt][nt] = __builtin_amdgcn_mfma_f32_16x16x32_bf16(ah[rt], bm[nt], acc[rt][nt], 0, 0, 0);
        acc[rt][nt] = __builtin_amdgcn_mfma_f32_16x16x32_bf16(am[rt], bh[nt], acc[rt][nt], 0, 0, 0);
      }
  }

#pragma unroll
  for (int nt = 0; nt < 4; nt++) {
    int col = wv * 64 + nt * 16 + lr;
    if (col < DD) {
      float bv = blv[col];
#pragma unroll
      for (int rt = 0; rt < 4; rt++) {
        int rowb = blockIdx.x * 64 + rt * 16 + 4 * g;
#pragma unroll
        for (int r = 0; r < 4; r++)
          if (rowb + r < NN) xlb[(size_t)(rowb + r) * DD + col] = bfh(acc[rt][nt][r] + bv);
      }
    } else {
      float bv = brv[col - DD];
#pragma unroll
      for (int rt = 0; rt < 4; rt++) {
        int rowb = blockIdx.x * 64 + rt * 16 + 4 * g;
#pragma unroll
        for (int r = 0; r < 4; r++)
          if (rowb + r < NN) xr[(size_t)(rowb + r) * DD + (col - DD)] = acc[rt][nt][r] + bv;
      }
    }
  }
}

// ---------- fused edge path v3 ----------
// One wave per dst node. Two 32-lane halves each process 2 edges/iteration
// (4 edges/iter/wave). Lane owns 4 dims (float4); head reduce = 8 lanes (3 DPP).
// Online softmax state per lane (its head). Halves merged once at end.
template <int SPLIT>
__global__ __launch_bounds__(256) void fused_edge_agg(
    const int* __restrict__ rowp, const int* __restrict__ colsrc,
    const unsigned short* __restrict__ xlb, const float* __restrict__ xr,
    const float* __restrict__ att, const float* __restrict__ bias,
    const float* __restrict__ gam, const float* __restrict__ bet,
    float* __restrict__ out, unsigned short* __restrict__ Oh,
    unsigned short* __restrict__ Om) {
  int node = __builtin_amdgcn_readfirstlane((blockIdx.x * 256 + threadIdx.x) >> 6);
  if (node >= NN) return;
  int l = threadIdx.x & 63;
  int half = l >> 5;
  int il = l & 31;
  int d0 = il << 2;                       // 4 dims per lane; head = il>>3

  float4 xrv = *(const float4*)(xr + (size_t)node * DD + d0);
  float4 atv = *(const float4*)(att + d0);
  atv.x *= LOG2E; atv.y *= LOG2E; atv.z *= LOG2E; atv.w *= LOG2E;  // exp2 domain
  int j0 = __builtin_amdgcn_readfirstlane(rowp[node]);
  int j1 = __builtin_amdgcn_readfirstlane(rowp[node + 1]);

  float m = -1e30f, den = 0.f;
  float a0 = 0.f, a1 = 0.f, a2 = 0.f, a3 = 0.f;
  const char* xlb8 = (const char*)xlb;
  const int goff = il << 3;               // 8B per lane within row

  for (int j = j0; j < j1; j += 4) {
    int e0 = j + (half << 1);
    int e1 = e0 + 1;
    bool v0 = e0 < j1, v1 = e1 < j1;
    int s0 = colsrc[v0 ? e0 : j];         // pre-scaled by 256
    int s1 = colsrc[v1 ? e1 : j];
    ushort4 g0 = *(const ushort4*)(xlb8 + (size_t)(unsigned)(s0 + goff));
    ushort4 g1 = *(const ushort4*)(xlb8 + (size_t)(unsigned)(s1 + goff));
    float x00 = bff(g0.x), x01 = bff(g0.y), x02 = bff(g0.z), x03 = bff(g0.w);
    float x10 = bff(g1.x), x11 = bff(g1.y), x12 = bff(g1.z), x13 = bff(g1.w);

    // edge 0 score
    float t0 = x00 + xrv.x, t1 = x01 + xrv.y, t2 = x02 + xrv.z, t3 = x03 + xrv.w;
    t0 = fmaxf(t0, 0.2f * t0); t1 = fmaxf(t1, 0.2f * t1);
    t2 = fmaxf(t2, 0.2f * t2); t3 = fmaxf(t3, 0.2f * t3);
    float p0 = ((t0 * atv.x + t1 * atv.y) + (t2 * atv.z + t3 * atv.w));
    // edge 1 score
    float u0 = x10 + xrv.x, u1 = x11 + xrv.y, u2 = x12 + xrv.z, u3 = x13 + xrv.w;
    u0 = fmaxf(u0, 0.2f * u0); u1 = fmaxf(u1, 0.2f * u1);
    u2 = fmaxf(u2, 0.2f * u2); u3 = fmaxf(u3, 0.2f * u3);
    float p1 = ((u0 * atv.x + u1 * atv.y) + (u2 * atv.z + u3 * atv.w));

    // 8-lane (per-head) reduce, both chains interleave in the VALU pipe
    p0 = dpp_add<0xB1>(p0);  p1 = dpp_add<0xB1>(p1);
    p0 = dpp_add<0x4E>(p0);  p1 = dpp_add<0x4E>(p1);
    p0 = dpp_add<0x141>(p0); p1 = dpp_add<0x141>(p1);
    p0 = v0 ? p0 : -1e30f;
    p1 = v1 ? p1 : -1e30f;

    // 2-edge local softmax + single online merge
    float m2 = fmaxf(p0, p1);
    float w0 = exp2f(p0 - m2), w1 = exp2f(p1 - m2);
    float sw = w0 + w1;
    float s0d = w0 * x00 + w1 * x10;
    float s1d = w0 * x01 + w1 * x11;
    float s2d = w0 * x02 + w1 * x12;
    float s3d = w0 * x03 + w1 * x13;
    float mn = fmaxf(m, m2);
    float ca = exp2f(m - mn), cb = exp2f(m2 - mn);
    den = den * ca + sw * cb;
    a0 = a0 * ca + s0d * cb;
    a1 = a1 * ca + s1d * cb;
    a2 = a2 * ca + s2d * cb;
    a3 = a3 * ca + s3d * cb;
    m = mn;
  }

  // merge the two halves (per-head state identical across partner lanes after this)
  {
    float om = __shfl_xor(m, 32), oden = __shfl_xor(den, 32);
    float o0 = __shfl_xor(a0, 32), o1 = __shfl_xor(a1, 32);
    float o2 = __shfl_xor(a2, 32), o3 = __shfl_xor(a3, 32);
    float mn = fmaxf(m, om);
    float ca = exp2f(m - mn), cb = exp2f(om - mn);
    den = den * ca + oden * cb;
    a0 = a0 * ca + o0 * cb;
    a1 = a1 * ca + o1 * cb;
    a2 = a2 * ca + o2 * cb;
    a3 = a3 * ca + o3 * cb;
  }

  float inv = 1.f / (den + 1e-16f);
  float4 bi = *(const float4*)(bias + d0);
  float vx0 = a0 * inv + bi.x, vx1 = a1 * inv + bi.y;
  float vx2 = a2 * inv + bi.z, vx3 = a3 * inv + bi.w;

  // LayerNorm over 128 dims (64-lane reduce counts everything twice -> /256)
  float s1 = (vx0 + vx1) + (vx2 + vx3);
  float s2 = (vx0 * vx0 + vx1 * vx1) + (vx2 * vx2 + vx3 * vx3);
  s1 = dpp_add<0xB1>(s1);  s2 = dpp_add<0xB1>(s2);
  s1 = dpp_add<0x4E>(s1);  s2 = dpp_add<0x4E>(s2);
  s1 = dpp_add<0x124>(s1); s2 = dpp_add<0x124>(s2);
  s1 = dpp_add<0x128>(s1); s2 = dpp_add<0x128>(s2);
  s1 += __shfl_xor(s1, 16); s2 += __shfl_xor(s2, 16);
  s1 += __shfl_xor(s1, 32); s2 += __shfl_xor(s2, 32);
  float mean = s1 * (1.f / 256.f);
  float var = s2 * (1.f / 256.f) - mean * mean;
  float rstd = rsqrtf(var + 1e-5f);
  float4 gm = *(const float4*)(gam + d0);
  float4 bt = *(const float4*)(bet + d0);
  float n0 = (vx0 - mean) * rstd * gm.x + bt.x;
  float n1 = (vx1 - mean) * rstd * gm.y + bt.y;
  float n2 = (vx2 - mean) * rstd * gm.z + bt.z;
  float n3 = (vx3 - mean) * rstd * gm.w + bt.w;
  n0 = n0 > 0.f ? n0 : expf(n0) - 1.f;
  n1 = n1 > 0.f ? n1 : expf(n1) - 1.f;
  n2 = n2 > 0.f ? n2 : expf(n2) - 1.f;
  n3 = n3 > 0.f ? n3 : expf(n3) - 1.f;

  if (half == 0) {                         // lanes 0-31 own the write
    if (SPLIT) {
      // fragment-major hi/mid write for next layer's A (4 contiguous k = d0..d0+3)
      int rb = node >> 4, lr16 = node & 15;
      int kt = d0 >> 5;
      int g = (d0 & 15) >> 2;
      int e0 = ((d0 >> 4) & 1) << 2;
      size_t off = ((((size_t)(rb * 4 + kt)) * 4 + g) * 16 + lr16) * 8 + e0;
      unsigned short h0 = bfh(n0), h1 = bfh(n1), h2 = bfh(n2), h3 = bfh(n3);
      ushort4 hv; hv.x = h0; hv.y = h1; hv.z = h2; hv.w = h3;
      ushort4 mv;
      mv.x = bfh(n0 - bff(h0)); mv.y = bfh(n1 - bff(h1));
      mv.z = bfh(n2 - bff(h2)); mv.w = bfh(n3 - bff(h3));
      *(ushort4*)(Oh + off) = hv;
      *(ushort4*)(Om + off) = mv;
    } else {
      float4 o; o.x = n0; o.y = n1; o.z = n2; o.w = n3;
      *(float4*)(out + (size_t)node * DD + d0) = o;
    }
  }
}

extern "C" void kernel_launch(void* const* d_in, const int* in_sizes, int n_in,
                              void* d_out, int out_size, void* d_ws, size_t ws_size,
                              hipStream_t stream) {
  const float* x  = (const float*)d_in[0];
  const int*   ei = (const int*)d_in[1];
  const float* Wl[2]   = {(const float*)d_in[2],  (const float*)d_in[10]};
  const float* bl[2]   = {(const float*)d_in[3],  (const float*)d_in[11]};
  const float* Wr[2]   = {(const float*)d_in[4],  (const float*)d_in[12]};
  const float* br[2]   = {(const float*)d_in[5],  (const float*)d_in[13]};
  const float* att[2]  = {(const float*)d_in[6],  (const float*)d_in[14]};
  const float* bias[2] = {(const float*)d_in[7],  (const float*)d_in[15]};
  const float* gam[2]  = {(const float*)d_in[8],  (const float*)d_in[16]};
  const float* bet[2]  = {(const float*)d_in[9],  (const float*)d_in[17]};
  float* out = (float*)d_out;

  char* w = (char*)d_ws;
  auto carve = [&](size_t bytes) {
    char* p = w;
    w += (bytes + 255) & ~(size_t)255;
    return p;
  };
  unsigned short* xlb = (unsigned short*)carve((size_t)NN * DD * 2);
  float* xr     = (float*)carve((size_t)NN * DD * 4);
  int*   deg    = (int*)carve((size_t)NN * 4);
  int*   cur    = (int*)carve((size_t)NN * 4);
  int*   rowp   = (int*)carve((size_t)(NN + 1) * 4);
  int*   colsrc = (int*)carve((size_t)NE * 4);
  int*   bsum   = (int*)carve((size_t)SCAN_B * 4);
  int*   boff   = (int*)carve((size_t)SCAN_B * 4);
  unsigned short* Ah = (unsigned short*)carve((size_t)RB_PAD * 2048 * 2);
  unsigned short* Am = (unsigned short*)carve((size_t)RB_PAD * 2048 * 2);
  unsigned short* Bh = (unsigned short*)carve((size_t)4096 * 8 * 2);
  unsigned short* Bm = (unsigned short*)carve((size_t)4096 * 8 * 2);

  // CSR build (recomputed every call — deterministic, no cross-call state)
  hipMemsetAsync(deg, 0, (size_t)NN * 4, stream);
  hipMemsetAsync(cur, 0, (size_t)NN * 4, stream);
  count_deg<<<(NE + 255) / 256, 256, 0, stream>>>(ei, deg);
  scan_partial<<<SCAN_B, SCAN_T, 0, stream>>>(deg, rowp, bsum);
  scan_bsums<<<1, 128, 0, stream>>>(bsum, boff, rowp);
  scan_add<<<SCAN_B, SCAN_T, 0, stream>>>(rowp, boff);
  scatter_src<<<(NE + 255) / 256, 256, 0, stream>>>(ei, rowp, cur, colsrc);

  // layer-0 input split (layer-1's split is produced by fused_edge_agg<1>)
  prep_a<<<RB_CNT, 256, 0, stream>>>(x, Ah, Am);

  for (int l = 0; l < 2; l++) {
    prep_w<<<16, 256, 0, stream>>>(Wl[l], Wr[l], Bh, Bm);
    dual_gemm_mfma<<<(NN + 63) / 64, 256, 0, stream>>>(Ah, Am, Bh, Bm, bl[l], br[l], xlb, xr);
    if (l == 0) {
      fused_edge_agg<1><<<(NN * 64 + 255) / 256, 256, 0, stream>>>(
          rowp, colsrc, xlb, xr, att[l], bias[l], gam[l], bet[l], out, Ah, Am);
    } else {
      fused_edge_agg<0><<<(NN * 64 + 255) / 256, 256, 0, stream>>>(
          rowp, colsrc, xlb, xr, att[l], bias[l], gam[l], bet[l], out, Ah, Am);
    }
  }
}

// Round 12
// 236.240 us; speedup vs baseline: 1.9355x; 1.1354x over previous
//
#include <hip/hip_runtime.h>

#define NN 50000
#define NE 600000
#define DD 128
#define NH 4
#define RB_CNT 3125   // NN/16 (exact)
#define RB_PAD 3128

#define SCAN_T 512
#define SCAN_B ((NN + SCAN_T - 1) / SCAN_T)

#define LOG2E 1.44269504088896340736f

typedef short s16x8 __attribute__((ext_vector_type(8)));
typedef float f32x4 __attribute__((ext_vector_type(4)));

// fp32 -> bf16 (RNE) and back
__device__ __forceinline__ unsigned short bfh(float f) {
  unsigned u = __float_as_uint(f);
  return (unsigned short)((u + 0x7fffu + ((u >> 16) & 1u)) >> 16);
}
__device__ __forceinline__ float bff(unsigned short h) {
  return __uint_as_float(((unsigned)h) << 16);
}

// cross-lane add via DPP. 0xB1 quad xor1, 0x4E quad xor2, 0x141 row_half_mirror,
// 0x124/0x128 row_ror:4/:8.
template <int CTRL>
__device__ __forceinline__ float dpp_add(float x) {
  int y = __builtin_amdgcn_update_dpp(0, __float_as_int(x), CTRL, 0xf, 0xf, true);
  return x + __int_as_float(y);
}

// ---------- CSR build ----------
__global__ void count_deg(const int* __restrict__ ei, int* __restrict__ deg) {
  int e = blockIdx.x * 256 + threadIdx.x;
  if (e < NE) atomicAdd(deg + ei[NE + e], 1);
}

__global__ __launch_bounds__(SCAN_T) void scan_partial(
    const int* __restrict__ deg, int* __restrict__ rowp, int* __restrict__ bsum) {
  __shared__ int buf[SCAN_T];
  int b = blockIdx.x, t = threadIdx.x;
  int i = b * SCAN_T + t;
  int v = (i < NN) ? deg[i] : 0;
  buf[t] = v;
  __syncthreads();
  for (int o = 1; o < SCAN_T; o <<= 1) {
    int add = (t >= o) ? buf[t - o] : 0;
    __syncthreads();
    buf[t] += add;
    __syncthreads();
  }
  if (i < NN) rowp[i] = buf[t] - v;
  if (t == SCAN_T - 1) bsum[b] = buf[t];
}

__global__ __launch_bounds__(128) void scan_bsums(
    int* __restrict__ bsum, int* __restrict__ boff, int* __restrict__ rowp) {
  __shared__ int buf[128];
  int t = threadIdx.x;
  int v = (t < SCAN_B) ? bsum[t] : 0;
  buf[t] = v;
  __syncthreads();
  for (int o = 1; o < 128; o <<= 1) {
    int add = (t >= o) ? buf[t - o] : 0;
    __syncthreads();
    buf[t] += add;
    __syncthreads();
  }
  if (t < SCAN_B) boff[t] = buf[t] - v;
  if (t == 127) rowp[NN] = buf[t];
}

__global__ __launch_bounds__(SCAN_T) void scan_add(
    int* __restrict__ rowp, const int* __restrict__ boff) {
  int b = blockIdx.x, t = threadIdx.x;
  int i = b * SCAN_T + t;
  if (i < NN) rowp[i] += boff[b];
}

// store src * 256 (bf16 row byte-stride)
__global__ void scatter_src(const int* __restrict__ ei, const int* __restrict__ rowp,
                            int* __restrict__ cur, int* __restrict__ colsrc) {
  int e = blockIdx.x * 256 + threadIdx.x;
  if (e < NE) {
    int d = ei[NE + e];
    int p = atomicAdd(cur + d, 1);
    colsrc[rowp[d] + p] = ei[e] << 8;
  }
}

// ---------- A prep: fp32 -> fragment-major bf16 hi/mid ----------
__global__ __launch_bounds__(256) void prep_a(
    const float* __restrict__ h, unsigned short* __restrict__ Ah,
    unsigned short* __restrict__ Am) {
  int tid = blockIdx.x * 256 + threadIdx.x;
  if (tid >= RB_CNT * 256) return;
  int lr = tid & 15;
  int g = (tid >> 4) & 3;
  int kt = (tid >> 6) & 3;
  int rb = tid >> 8;
  int row = rb * 16 + lr;
  const float* p = h + (size_t)row * DD + kt * 32 + 4 * g;
  float4 f0 = *(const float4*)(p);
  float4 f1 = *(const float4*)(p + 16);
  float fs[8] = {f0.x, f0.y, f0.z, f0.w, f1.x, f1.y, f1.z, f1.w};
  s16x8 hi, mid;
#pragma unroll
  for (int e = 0; e < 8; e++) {
    unsigned short hh = bfh(fs[e]);
    hi[e] = (short)hh;
    mid[e] = (short)bfh(fs[e] - bff(hh));
  }
  *(s16x8*)(Ah + (size_t)tid * 8) = hi;
  *(s16x8*)(Am + (size_t)tid * 8) = mid;
}

// ---------- W prep: transpose + split, fragment-major ----------
__global__ __launch_bounds__(256) void prep_w(
    const float* __restrict__ Wl, const float* __restrict__ Wr,
    unsigned short* __restrict__ Bh, unsigned short* __restrict__ Bm) {
  int tid = blockIdx.x * 256 + threadIdx.x;
  if (tid >= 4096) return;
  int lr = tid & 15;
  int g = (tid >> 4) & 3;
  int kt = (tid >> 6) & 3;
  int ct = tid >> 8;
  int col = ct * 16 + lr;
  const float* W = (col < DD) ? Wl : Wr;
  int cc = (col < DD) ? col : col - DD;
  s16x8 hi, mid;
#pragma unroll
  for (int e = 0; e < 8; e++) {
    int k = kt * 32 + ((e >> 2) << 4) + 4 * g + (e & 3);
    float w = W[(size_t)k * DD + cc];
    unsigned short hh = bfh(w);
    hi[e] = (short)hh;
    mid[e] = (short)bfh(w - bff(hh));
  }
  *(s16x8*)(Bh + (size_t)tid * 8) = hi;
  *(s16x8*)(Bm + (size_t)tid * 8) = mid;
}

// ---------- dual GEMM v2: 32-row blocks for occupancy ----------
// block: 32 rows x 256 cols, 4 waves; wave: 32x64 (acc[2][4]); ~100 VGPR.
__global__ __launch_bounds__(256, 2) void dual_gemm_mfma(
    const unsigned short* __restrict__ Ah, const unsigned short* __restrict__ Am,
    const unsigned short* __restrict__ Bh, const unsigned short* __restrict__ Bm,
    const float* __restrict__ blv, const float* __restrict__ brv,
    unsigned short* __restrict__ xlb, float* __restrict__ xr) {
  const int tid = threadIdx.x;
  const int lane = tid & 63;
  const int wv = tid >> 6;
  const int lr = lane & 15;
  const int g = lane >> 4;
  const int rb0 = blockIdx.x * 2;

  f32x4 acc[2][4];
#pragma unroll
  for (int rt = 0; rt < 2; rt++)
#pragma unroll
    for (int nt = 0; nt < 4; nt++)
#pragma unroll
      for (int e = 0; e < 4; e++) acc[rt][nt][e] = 0.f;

#pragma unroll
  for (int kt = 0; kt < 4; kt++) {
    s16x8 ah[2], am[2], bh[4], bm[4];
#pragma unroll
    for (int rt = 0; rt < 2; rt++) {
      size_t off = ((((size_t)((rb0 + rt) * 4 + kt)) * 4 + g) * 16 + lr) * 8;
      ah[rt] = *(const s16x8*)(Ah + off);
      am[rt] = *(const s16x8*)(Am + off);
    }
#pragma unroll
    for (int nt = 0; nt < 4; nt++) {
      int ct = wv * 4 + nt;
      size_t off = ((((size_t)(ct * 4 + kt)) * 4 + g) * 16 + lr) * 8;
      bh[nt] = *(const s16x8*)(Bh + off);
      bm[nt] = *(const s16x8*)(Bm + off);
    }
#pragma unroll
    for (int rt = 0; rt < 2; rt++)
#pragma unroll
      for (int nt = 0; nt < 4; nt++) {
        acc[rt][nt] = __builtin_amdgcn_mfma_f32_16x16x32_bf16(ah[rt], bh[nt], acc[rt][nt], 0, 0, 0);
        acc[rt][nt] = __builtin_amdgcn_mfma_f32_16x16x32_bf16(ah[rt], bm[nt], acc[rt][nt], 0, 0, 0);
        acc[rt][nt] = __builtin_amdgcn_mfma_f32_16x16x32_bf16(am[rt], bh[nt], acc[rt][nt], 0, 0, 0);
      }
  }

#pragma unroll
  for (int nt = 0; nt < 4; nt++) {
    int col = wv * 64 + nt * 16 + lr;
    if (col < DD) {
      float bv = blv[col];
#pragma unroll
      for (int rt = 0; rt < 2; rt++) {
        int rowb = blockIdx.x * 32 + rt * 16 + 4 * g;
#pragma unroll
        for (int r = 0; r < 4; r++)
          if (rowb + r < NN) xlb[(size_t)(rowb + r) * DD + col] = bfh(acc[rt][nt][r] + bv);
      }
    } else {
      float bv = brv[col - DD];
#pragma unroll
      for (int rt = 0; rt < 2; rt++) {
        int rowb = blockIdx.x * 32 + rt * 16 + 4 * g;
#pragma unroll
        for (int r = 0; r < 4; r++)
          if (rowb + r < NN) xr[(size_t)(rowb + r) * DD + (col - DD)] = acc[rt][nt][r] + bv;
      }
    }
  }
}

// ---------- fused edge path v4: no-max softmax (bounded scores), direct exp2 ----------
// One wave per dst node; two 32-lane halves, 2 edges each per iter; lane owns 4 dims.
// No running max: scores bounded (|p| << 85), exp2 accumulated directly ->
// no loop-carried softmax chain, pure FMA accumulation.
template <int SPLIT>
__global__ __launch_bounds__(256) void fused_edge_agg(
    const int* __restrict__ rowp, const int* __restrict__ colsrc,
    const unsigned short* __restrict__ xlb, const float* __restrict__ xr,
    const float* __restrict__ att, const float* __restrict__ bias,
    const float* __restrict__ gam, const float* __restrict__ bet,
    float* __restrict__ out, unsigned short* __restrict__ Oh,
    unsigned short* __restrict__ Om) {
  int node = __builtin_amdgcn_readfirstlane((blockIdx.x * 256 + threadIdx.x) >> 6);
  if (node >= NN) return;
  int l = threadIdx.x & 63;
  int half = l >> 5;
  int il = l & 31;
  int d0 = il << 2;                       // 4 dims per lane; head = il>>3

  float4 xrv = *(const float4*)(xr + (size_t)node * DD + d0);
  float4 atv = *(const float4*)(att + d0);
  atv.x *= LOG2E; atv.y *= LOG2E; atv.z *= LOG2E; atv.w *= LOG2E;  // exp2 domain
  int j0 = __builtin_amdgcn_readfirstlane(rowp[node]);
  int j1 = __builtin_amdgcn_readfirstlane(rowp[node + 1]);

  float den = 0.f;
  float a0 = 0.f, a1 = 0.f, a2 = 0.f, a3 = 0.f;
  const char* xlb8 = (const char*)xlb;
  const int goff = il << 3;               // 8B per lane within row

  for (int j = j0; j < j1; j += 4) {
    int e0 = j + (half << 1);
    int e1 = e0 + 1;
    bool v0 = e0 < j1, v1 = e1 < j1;
    int s0 = colsrc[v0 ? e0 : j];         // pre-scaled by 256
    int s1 = colsrc[v1 ? e1 : j];
    ushort4 g0 = *(const ushort4*)(xlb8 + (size_t)(unsigned)(s0 + goff));
    ushort4 g1 = *(const ushort4*)(xlb8 + (size_t)(unsigned)(s1 + goff));
    float x00 = bff(g0.x), x01 = bff(g0.y), x02 = bff(g0.z), x03 = bff(g0.w);
    float x10 = bff(g1.x), x11 = bff(g1.y), x12 = bff(g1.z), x13 = bff(g1.w);

    float t0 = x00 + xrv.x, t1 = x01 + xrv.y, t2 = x02 + xrv.z, t3 = x03 + xrv.w;
    t0 = fmaxf(t0, 0.2f * t0); t1 = fmaxf(t1, 0.2f * t1);
    t2 = fmaxf(t2, 0.2f * t2); t3 = fmaxf(t3, 0.2f * t3);
    float p0 = ((t0 * atv.x + t1 * atv.y) + (t2 * atv.z + t3 * atv.w));
    float u0 = x10 + xrv.x, u1 = x11 + xrv.y, u2 = x12 + xrv.z, u3 = x13 + xrv.w;
    u0 = fmaxf(u0, 0.2f * u0); u1 = fmaxf(u1, 0.2f * u1);
    u2 = fmaxf(u2, 0.2f * u2); u3 = fmaxf(u3, 0.2f * u3);
    float p1 = ((u0 * atv.x + u1 * atv.y) + (u2 * atv.z + u3 * atv.w));

    // 8-lane (per-head) reduce
    p0 = dpp_add<0xB1>(p0);  p1 = dpp_add<0xB1>(p1);
    p0 = dpp_add<0x4E>(p0);  p1 = dpp_add<0x4E>(p1);
    p0 = dpp_add<0x141>(p0); p1 = dpp_add<0x141>(p1);

    float w0 = v0 ? exp2f(p0) : 0.f;
    float w1 = v1 ? exp2f(p1) : 0.f;
    den += w0 + w1;
    a0 += w0 * x00 + w1 * x10;
    a1 += w0 * x01 + w1 * x11;
    a2 += w0 * x02 + w1 * x12;
    a3 += w0 * x03 + w1 * x13;
  }

  // merge the two halves (plain sums now)
  den += __shfl_xor(den, 32);
  a0 += __shfl_xor(a0, 32);
  a1 += __shfl_xor(a1, 32);
  a2 += __shfl_xor(a2, 32);
  a3 += __shfl_xor(a3, 32);

  float inv = 1.f / (den + 1e-16f);
  float4 bi = *(const float4*)(bias + d0);
  float vx0 = a0 * inv + bi.x, vx1 = a1 * inv + bi.y;
  float vx2 = a2 * inv + bi.z, vx3 = a3 * inv + bi.w;

  // LayerNorm over 128 dims (64-lane reduce counts everything twice -> /256)
  float s1 = (vx0 + vx1) + (vx2 + vx3);
  float s2 = (vx0 * vx0 + vx1 * vx1) + (vx2 * vx2 + vx3 * vx3);
  s1 = dpp_add<0xB1>(s1);  s2 = dpp_add<0xB1>(s2);
  s1 = dpp_add<0x4E>(s1);  s2 = dpp_add<0x4E>(s2);
  s1 = dpp_add<0x124>(s1); s2 = dpp_add<0x124>(s2);
  s1 = dpp_add<0x128>(s1); s2 = dpp_add<0x128>(s2);
  s1 += __shfl_xor(s1, 16); s2 += __shfl_xor(s2, 16);
  s1 += __shfl_xor(s1, 32); s2 += __shfl_xor(s2, 32);
  float mean = s1 * (1.f / 256.f);
  float var = s2 * (1.f / 256.f) - mean * mean;
  float rstd = rsqrtf(var + 1e-5f);
  float4 gm = *(const float4*)(gam + d0);
  float4 bt = *(const float4*)(bet + d0);
  float n0 = (vx0 - mean) * rstd * gm.x + bt.x;
  float n1 = (vx1 - mean) * rstd * gm.y + bt.y;
  float n2 = (vx2 - mean) * rstd * gm.z + bt.z;
  float n3 = (vx3 - mean) * rstd * gm.w + bt.w;
  n0 = n0 > 0.f ? n0 : expf(n0) - 1.f;
  n1 = n1 > 0.f ? n1 : expf(n1) - 1.f;
  n2 = n2 > 0.f ? n2 : expf(n2) - 1.f;
  n3 = n3 > 0.f ? n3 : expf(n3) - 1.f;

  if (half == 0) {                         // lanes 0-31 own the write
    if (SPLIT) {
      int rb = node >> 4, lr16 = node & 15;
      int kt = d0 >> 5;
      int g = (d0 & 15) >> 2;
      int e0 = ((d0 >> 4) & 1) << 2;
      size_t off = ((((size_t)(rb * 4 + kt)) * 4 + g) * 16 + lr16) * 8 + e0;
      unsigned short h0 = bfh(n0), h1 = bfh(n1), h2 = bfh(n2), h3 = bfh(n3);
      ushort4 hv; hv.x = h0; hv.y = h1; hv.z = h2; hv.w = h3;
      ushort4 mv;
      mv.x = bfh(n0 - bff(h0)); mv.y = bfh(n1 - bff(h1));
      mv.z = bfh(n2 - bff(h2)); mv.w = bfh(n3 - bff(h3));
      *(ushort4*)(Oh + off) = hv;
      *(ushort4*)(Om + off) = mv;
    } else {
      float4 o; o.x = n0; o.y = n1; o.z = n2; o.w = n3;
      *(float4*)(out + (size_t)node * DD + d0) = o;
    }
  }
}

extern "C" void kernel_launch(void* const* d_in, const int* in_sizes, int n_in,
                              void* d_out, int out_size, void* d_ws, size_t ws_size,
                              hipStream_t stream) {
  const float* x  = (const float*)d_in[0];
  const int*   ei = (const int*)d_in[1];
  const float* Wl[2]   = {(const float*)d_in[2],  (const float*)d_in[10]};
  const float* bl[2]   = {(const float*)d_in[3],  (const float*)d_in[11]};
  const float* Wr[2]   = {(const float*)d_in[4],  (const float*)d_in[12]};
  const float* br[2]   = {(const float*)d_in[5],  (const float*)d_in[13]};
  const float* att[2]  = {(const float*)d_in[6],  (const float*)d_in[14]};
  const float* bias[2] = {(const float*)d_in[7],  (const float*)d_in[15]};
  const float* gam[2]  = {(const float*)d_in[8],  (const float*)d_in[16]};
  const float* bet[2]  = {(const float*)d_in[9],  (const float*)d_in[17]};
  float* out = (float*)d_out;

  char* w = (char*)d_ws;
  auto carve = [&](size_t bytes) {
    char* p = w;
    w += (bytes + 255) & ~(size_t)255;
    return p;
  };
  unsigned short* xlb = (unsigned short*)carve((size_t)NN * DD * 2);
  float* xr     = (float*)carve((size_t)NN * DD * 4);
  int*   deg    = (int*)carve((size_t)NN * 4);
  int*   cur    = (int*)carve((size_t)NN * 4);
  int*   rowp   = (int*)carve((size_t)(NN + 1) * 4);
  int*   colsrc = (int*)carve((size_t)NE * 4);
  int*   bsum   = (int*)carve((size_t)SCAN_B * 4);
  int*   boff   = (int*)carve((size_t)SCAN_B * 4);
  unsigned short* Ah = (unsigned short*)carve((size_t)RB_PAD * 2048 * 2);
  unsigned short* Am = (unsigned short*)carve((size_t)RB_PAD * 2048 * 2);
  unsigned short* Bh = (unsigned short*)carve((size_t)4096 * 8 * 2);
  unsigned short* Bm = (unsigned short*)carve((size_t)4096 * 8 * 2);

  // CSR build (recomputed every call — deterministic, no cross-call state)
  hipMemsetAsync(deg, 0, (size_t)NN * 4, stream);
  hipMemsetAsync(cur, 0, (size_t)NN * 4, stream);
  count_deg<<<(NE + 255) / 256, 256, 0, stream>>>(ei, deg);
  scan_partial<<<SCAN_B, SCAN_T, 0, stream>>>(deg, rowp, bsum);
  scan_bsums<<<1, 128, 0, stream>>>(bsum, boff, rowp);
  scan_add<<<SCAN_B, SCAN_T, 0, stream>>>(rowp, boff);
  scatter_src<<<(NE + 255) / 256, 256, 0, stream>>>(ei, rowp, cur, colsrc);

  // layer-0 input split (layer-1's split is produced by fused_edge_agg<1>)
  prep_a<<<RB_CNT, 256, 0, stream>>>(x, Ah, Am);

  for (int l = 0; l < 2; l++) {
    prep_w<<<16, 256, 0, stream>>>(Wl[l], Wr[l], Bh, Bm);
    dual_gemm_mfma<<<(NN + 31) / 32, 256, 0, stream>>>(Ah, Am, Bh, Bm, bl[l], br[l], xlb, xr);
    if (l == 0) {
      fused_edge_agg<1><<<(NN * 64 + 255) / 256, 256, 0, stream>>>(
          rowp, colsrc, xlb, xr, att[l], bias[l], gam[l], bet[l], out, Ah, Am);
    } else {
      fused_edge_agg<0><<<(NN * 64 + 255) / 256, 256, 0, stream>>>(
          rowp, colsrc, xlb, xr, att[l], bias[l], gam[l], bet[l], out, Ah, Am);
    }
  }
}

// Round 14
// 220.892 us; speedup vs baseline: 2.0700x; 1.0695x over previous
//
#include <hip/hip_runtime.h>

#define NN 50000
#define NE 600000
#define DD 128
#define NH 4
#define RB_CNT 3125   // NN/16 (exact)
#define RB_PAD 3128

#define SCAN_T 512
#define SCAN_B ((NN + SCAN_T - 1) / SCAN_T)

#define LOG2E 1.44269504088896340736f

typedef short s16x8 __attribute__((ext_vector_type(8)));
typedef float f32x4 __attribute__((ext_vector_type(4)));

// fp32 -> bf16 (RNE) and back
__device__ __forceinline__ unsigned short bfh(float f) {
  unsigned u = __float_as_uint(f);
  return (unsigned short)((u + 0x7fffu + ((u >> 16) & 1u)) >> 16);
}
__device__ __forceinline__ float bff(unsigned short h) {
  return __uint_as_float(((unsigned)h) << 16);
}

// cross-lane add via DPP. 0xB1 quad xor1, 0x4E quad xor2, 0x141 row_half_mirror,
// 0x124/0x128 row_ror:4/:8.
template <int CTRL>
__device__ __forceinline__ float dpp_add(float x) {
  int y = __builtin_amdgcn_update_dpp(0, __float_as_int(x), CTRL, 0xf, 0xf, true);
  return x + __int_as_float(y);
}

// ---------- CSR build ----------
__global__ void count_deg(const int* __restrict__ ei, int* __restrict__ deg) {
  int e = blockIdx.x * 256 + threadIdx.x;
  if (e < NE) atomicAdd(deg + ei[NE + e], 1);
}

__global__ __launch_bounds__(SCAN_T) void scan_partial(
    const int* __restrict__ deg, int* __restrict__ rowp, int* __restrict__ bsum) {
  __shared__ int buf[SCAN_T];
  int b = blockIdx.x, t = threadIdx.x;
  int i = b * SCAN_T + t;
  int v = (i < NN) ? deg[i] : 0;
  buf[t] = v;
  __syncthreads();
  for (int o = 1; o < SCAN_T; o <<= 1) {
    int add = (t >= o) ? buf[t - o] : 0;
    __syncthreads();
    buf[t] += add;
    __syncthreads();
  }
  if (i < NN) rowp[i] = buf[t] - v;
  if (t == SCAN_T - 1) bsum[b] = buf[t];
}

__global__ __launch_bounds__(128) void scan_bsums(
    int* __restrict__ bsum, int* __restrict__ boff, int* __restrict__ rowp) {
  __shared__ int buf[128];
  int t = threadIdx.x;
  int v = (t < SCAN_B) ? bsum[t] : 0;
  buf[t] = v;
  __syncthreads();
  for (int o = 1; o < 128; o <<= 1) {
    int add = (t >= o) ? buf[t - o] : 0;
    __syncthreads();
    buf[t] += add;
    __syncthreads();
  }
  if (t < SCAN_B) boff[t] = buf[t] - v;
  if (t == 127) rowp[NN] = buf[t];
}

__global__ __launch_bounds__(SCAN_T) void scan_add(
    int* __restrict__ rowp, const int* __restrict__ boff) {
  int b = blockIdx.x, t = threadIdx.x;
  int i = b * SCAN_T + t;
  if (i < NN) rowp[i] += boff[b];
}

// store src * 256 (bf16 row byte-stride)
__global__ void scatter_src(const int* __restrict__ ei, const int* __restrict__ rowp,
                            int* __restrict__ cur, int* __restrict__ colsrc) {
  int e = blockIdx.x * 256 + threadIdx.x;
  if (e < NE) {
    int d = ei[NE + e];
    int p = atomicAdd(cur + d, 1);
    colsrc[rowp[d] + p] = ei[e] << 8;
  }
}

// ---------- A prep: fp32 -> fragment-major bf16 hi/mid ----------
__global__ __launch_bounds__(256) void prep_a(
    const float* __restrict__ h, unsigned short* __restrict__ Ah,
    unsigned short* __restrict__ Am) {
  int tid = blockIdx.x * 256 + threadIdx.x;
  if (tid >= RB_CNT * 256) return;
  int lr = tid & 15;
  int g = (tid >> 4) & 3;
  int kt = (tid >> 6) & 3;
  int rb = tid >> 8;
  int row = rb * 16 + lr;
  const float* p = h + (size_t)row * DD + kt * 32 + 4 * g;
  float4 f0 = *(const float4*)(p);
  float4 f1 = *(const float4*)(p + 16);
  float fs[8] = {f0.x, f0.y, f0.z, f0.w, f1.x, f1.y, f1.z, f1.w};
  s16x8 hi, mid;
#pragma unroll
  for (int e = 0; e < 8; e++) {
    unsigned short hh = bfh(fs[e]);
    hi[e] = (short)hh;
    mid[e] = (short)bfh(fs[e] - bff(hh));
  }
  *(s16x8*)(Ah + (size_t)tid * 8) = hi;
  *(s16x8*)(Am + (size_t)tid * 8) = mid;
}

// ---------- W prep: both layers in one dispatch ----------
// per-layer 4096 fragment slots; layer = tid>>12
__global__ __launch_bounds__(256) void prep_w(
    const float* __restrict__ Wl0, const float* __restrict__ Wr0,
    const float* __restrict__ Wl1, const float* __restrict__ Wr1,
    unsigned short* __restrict__ Bh, unsigned short* __restrict__ Bm) {
  int tid = blockIdx.x * 256 + threadIdx.x;
  if (tid >= 8192) return;
  int lay = tid >> 12;
  int t = tid & 4095;
  int lr = t & 15;
  int g = (t >> 4) & 3;
  int kt = (t >> 6) & 3;
  int ct = t >> 8;
  int col = ct * 16 + lr;
  const float* W = (col < DD) ? (lay ? Wl1 : Wl0) : (lay ? Wr1 : Wr0);
  int cc = (col < DD) ? col : col - DD;
  s16x8 hi, mid;
#pragma unroll
  for (int e = 0; e < 8; e++) {
    int k = kt * 32 + ((e >> 2) << 4) + 4 * g + (e & 3);
    float w = W[(size_t)k * DD + cc];
    unsigned short hh = bfh(w);
    hi[e] = (short)hh;
    mid[e] = (short)bfh(w - bff(hh));
  }
  *(s16x8*)(Bh + (size_t)tid * 8) = hi;
  *(s16x8*)(Bm + (size_t)tid * 8) = mid;
}

// ---------- dual GEMM: split-bf16 MFMA; xl AND xr written as bf16 ----------
// block: 32 rows x 256 cols, 4 waves; wave: 32x64 (acc[2][4]).
__global__ __launch_bounds__(256, 2) void dual_gemm_mfma(
    const unsigned short* __restrict__ Ah, const unsigned short* __restrict__ Am,
    const unsigned short* __restrict__ Bh, const unsigned short* __restrict__ Bm,
    const float* __restrict__ blv, const float* __restrict__ brv,
    unsigned short* __restrict__ xlb, unsigned short* __restrict__ xrb) {
  const int tid = threadIdx.x;
  const int lane = tid & 63;
  const int wv = tid >> 6;
  const int lr = lane & 15;
  const int g = lane >> 4;
  const int rb0 = blockIdx.x * 2;

  f32x4 acc[2][4];
#pragma unroll
  for (int rt = 0; rt < 2; rt++)
#pragma unroll
    for (int nt = 0; nt < 4; nt++)
#pragma unroll
      for (int e = 0; e < 4; e++) acc[rt][nt][e] = 0.f;

#pragma unroll
  for (int kt = 0; kt < 4; kt++) {
    s16x8 ah[2], am[2], bh[4], bm[4];
#pragma unroll
    for (int rt = 0; rt < 2; rt++) {
      size_t off = ((((size_t)((rb0 + rt) * 4 + kt)) * 4 + g) * 16 + lr) * 8;
      ah[rt] = *(const s16x8*)(Ah + off);
      am[rt] = *(const s16x8*)(Am + off);
    }
#pragma unroll
    for (int nt = 0; nt < 4; nt++) {
      int ct = wv * 4 + nt;
      size_t off = ((((size_t)(ct * 4 + kt)) * 4 + g) * 16 + lr) * 8;
      bh[nt] = *(const s16x8*)(Bh + off);
      bm[nt] = *(const s16x8*)(Bm + off);
    }
#pragma unroll
    for (int rt = 0; rt < 2; rt++)
#pragma unroll
      for (int nt = 0; nt < 4; nt++) {
        acc[rt][nt] = __builtin_amdgcn_mfma_f32_16x16x32_bf16(ah[rt], bh[nt], acc[rt][nt], 0, 0, 0);
        acc[rt][nt] = __builtin_amdgcn_mfma_f32_16x16x32_bf16(ah[rt], bm[nt], acc[rt][nt], 0, 0, 0);
        acc[rt][nt] = __builtin_amdgcn_mfma_f32_16x16x32_bf16(am[rt], bh[nt], acc[rt][nt], 0, 0, 0);
      }
  }

#pragma unroll
  for (int nt = 0; nt < 4; nt++) {
    int col = wv * 64 + nt * 16 + lr;
    unsigned short* dst = (col < DD) ? (xlb + col) : (xrb + (col - DD));
    float bv = (col < DD) ? blv[col] : brv[col - DD];
#pragma unroll
    for (int rt = 0; rt < 2; rt++) {
      int rowb = blockIdx.x * 32 + rt * 16 + 4 * g;
#pragma unroll
      for (int r = 0; r < 4; r++)
        if (rowb + r < NN) dst[(size_t)(rowb + r) * DD] = bfh(acc[rt][nt][r] + bv);
    }
  }
}

// ---------- fused edge path v5: half-wave (32 lanes) per node ----------
// Lane owns 4 dims (128/32). 2 edges per iteration. No-max softmax (bounded
// scores, direct exp2). Per-half loop bounds via exec masking.
template <int SPLIT>
__global__ __launch_bounds__(256) void fused_edge_agg(
    const int* __restrict__ rowp, const int* __restrict__ colsrc,
    const unsigned short* __restrict__ xlb, const unsigned short* __restrict__ xrb,
    const float* __restrict__ att, const float* __restrict__ bias,
    const float* __restrict__ gam, const float* __restrict__ bet,
    float* __restrict__ out, unsigned short* __restrict__ Oh,
    unsigned short* __restrict__ Om) {
  int node = (blockIdx.x * 256 + threadIdx.x) >> 5;   // half-wave id
  if (node >= NN) return;
  int il = threadIdx.x & 31;
  int d0 = il << 2;                       // 4 dims per lane; head = il>>3

  ushort4 xru = *(const ushort4*)(xrb + (size_t)node * DD + d0);
  float4 xrv; xrv.x = bff(xru.x); xrv.y = bff(xru.y);
  xrv.z = bff(xru.z); xrv.w = bff(xru.w);
  float4 atv = *(const float4*)(att + d0);
  atv.x *= LOG2E; atv.y *= LOG2E; atv.z *= LOG2E; atv.w *= LOG2E;
  int j0 = rowp[node];
  int j1 = rowp[node + 1];

  float den = 0.f;
  float a0 = 0.f, a1 = 0.f, a2 = 0.f, a3 = 0.f;
  const char* xlb8 = (const char*)xlb;
  const int goff = il << 3;               // 8B per lane within row

  for (int j = j0; j < j1; j += 2) {
    bool v1 = (j + 1) < j1;
    int s0 = colsrc[j];                   // pre-scaled by 256
    int s1 = colsrc[v1 ? j + 1 : j];
    ushort4 g0 = *(const ushort4*)(xlb8 + (size_t)(unsigned)(s0 + goff));
    ushort4 g1 = *(const ushort4*)(xlb8 + (size_t)(unsigned)(s1 + goff));
    float x00 = bff(g0.x), x01 = bff(g0.y), x02 = bff(g0.z), x03 = bff(g0.w);
    float x10 = bff(g1.x), x11 = bff(g1.y), x12 = bff(g1.z), x13 = bff(g1.w);

    float t0 = x00 + xrv.x, t1 = x01 + xrv.y, t2 = x02 + xrv.z, t3 = x03 + xrv.w;
    t0 = fmaxf(t0, 0.2f * t0); t1 = fmaxf(t1, 0.2f * t1);
    t2 = fmaxf(t2, 0.2f * t2); t3 = fmaxf(t3, 0.2f * t3);
    float p0 = ((t0 * atv.x + t1 * atv.y) + (t2 * atv.z + t3 * atv.w));
    float u0 = x10 + xrv.x, u1 = x11 + xrv.y, u2 = x12 + xrv.z, u3 = x13 + xrv.w;
    u0 = fmaxf(u0, 0.2f * u0); u1 = fmaxf(u1, 0.2f * u1);
    u2 = fmaxf(u2, 0.2f * u2); u3 = fmaxf(u3, 0.2f * u3);
    float p1 = ((u0 * atv.x + u1 * atv.y) + (u2 * atv.z + u3 * atv.w));

    // 8-lane (per-head) reduce
    p0 = dpp_add<0xB1>(p0);  p1 = dpp_add<0xB1>(p1);
    p0 = dpp_add<0x4E>(p0);  p1 = dpp_add<0x4E>(p1);
    p0 = dpp_add<0x141>(p0); p1 = dpp_add<0x141>(p1);

    float w0 = exp2f(p0);
    float w1 = v1 ? exp2f(p1) : 0.f;
    den += w0 + w1;
    a0 += w0 * x00 + w1 * x10;
    a1 += w0 * x01 + w1 * x11;
    a2 += w0 * x02 + w1 * x12;
    a3 += w0 * x03 + w1 * x13;
  }

  float inv = 1.f / (den + 1e-16f);
  float4 bi = *(const float4*)(bias + d0);
  float vx0 = a0 * inv + bi.x, vx1 = a1 * inv + bi.y;
  float vx2 = a2 * inv + bi.z, vx3 = a3 * inv + bi.w;

  // LayerNorm over 128 dims within the 32-lane half (each dim once -> /128)
  float s1 = (vx0 + vx1) + (vx2 + vx3);
  float s2 = (vx0 * vx0 + vx1 * vx1) + (vx2 * vx2 + vx3 * vx3);
  s1 = dpp_add<0xB1>(s1);  s2 = dpp_add<0xB1>(s2);
  s1 = dpp_add<0x4E>(s1);  s2 = dpp_add<0x4E>(s2);
  s1 = dpp_add<0x124>(s1); s2 = dpp_add<0x124>(s2);
  s1 = dpp_add<0x128>(s1); s2 = dpp_add<0x128>(s2);
  s1 += __shfl_xor(s1, 16); s2 += __shfl_xor(s2, 16);
  float mean = s1 * (1.f / 128.f);
  float var = s2 * (1.f / 128.f) - mean * mean;
  float rstd = rsqrtf(var + 1e-5f);
  float4 gm = *(const float4*)(gam + d0);
  float4 bt = *(const float4*)(bet + d0);
  float n0 = (vx0 - mean) * rstd * gm.x + bt.x;
  float n1 = (vx1 - mean) * rstd * gm.y + bt.y;
  float n2 = (vx2 - mean) * rstd * gm.z + bt.z;
  float n3 = (vx3 - mean) * rstd * gm.w + bt.w;
  n0 = n0 > 0.f ? n0 : expf(n0) - 1.f;
  n1 = n1 > 0.f ? n1 : expf(n1) - 1.f;
  n2 = n2 > 0.f ? n2 : expf(n2) - 1.f;
  n3 = n3 > 0.f ? n3 : expf(n3) - 1.f;

  if (SPLIT) {
    int rb = node >> 4, lr16 = node & 15;
    int kt = d0 >> 5;
    int g = (d0 & 15) >> 2;
    int e0 = ((d0 >> 4) & 1) << 2;
    size_t off = ((((size_t)(rb * 4 + kt)) * 4 + g) * 16 + lr16) * 8 + e0;
    unsigned short h0 = bfh(n0), h1 = bfh(n1), h2 = bfh(n2), h3 = bfh(n3);
    ushort4 hv; hv.x = h0; hv.y = h1; hv.z = h2; hv.w = h3;
    ushort4 mv;
    mv.x = bfh(n0 - bff(h0)); mv.y = bfh(n1 - bff(h1));
    mv.z = bfh(n2 - bff(h2)); mv.w = bfh(n3 - bff(h3));
    *(ushort4*)(Oh + off) = hv;
    *(ushort4*)(Om + off) = mv;
  } else {
    float4 o; o.x = n0; o.y = n1; o.z = n2; o.w = n3;
    *(float4*)(out + (size_t)node * DD + d0) = o;
  }
}

extern "C" void kernel_launch(void* const* d_in, const int* in_sizes, int n_in,
                              void* d_out, int out_size, void* d_ws, size_t ws_size,
                              hipStream_t stream) {
  const float* x  = (const float*)d_in[0];
  const int*   ei = (const int*)d_in[1];
  const float* Wl[2]   = {(const float*)d_in[2],  (const float*)d_in[10]};
  const float* bl[2]   = {(const float*)d_in[3],  (const float*)d_in[11]};
  const float* Wr[2]   = {(const float*)d_in[4],  (const float*)d_in[12]};
  const float* br[2]   = {(const float*)d_in[5],  (const float*)d_in[13]};
  const float* att[2]  = {(const float*)d_in[6],  (const float*)d_in[14]};
  const float* bias[2] = {(const float*)d_in[7],  (const float*)d_in[15]};
  const float* gam[2]  = {(const float*)d_in[8],  (const float*)d_in[16]};
  const float* bet[2]  = {(const float*)d_in[9],  (const float*)d_in[17]};
  float* out = (float*)d_out;

  char* w = (char*)d_ws;
  auto carve = [&](size_t bytes) {
    char* p = w;
    w += (bytes + 255) & ~(size_t)255;
    return p;
  };
  unsigned short* xlb = (unsigned short*)carve((size_t)NN * DD * 2);
  unsigned short* xrb = (unsigned short*)carve((size_t)NN * DD * 2);
  int*   deg    = (int*)carve((size_t)NN * 4);
  int*   cur    = (int*)carve((size_t)NN * 4);
  int*   rowp   = (int*)carve((size_t)(NN + 1) * 4);
  int*   colsrc = (int*)carve((size_t)NE * 4);
  int*   bsum   = (int*)carve((size_t)SCAN_B * 4);
  int*   boff   = (int*)carve((size_t)SCAN_B * 4);
  unsigned short* Ah = (unsigned short*)carve((size_t)RB_PAD * 2048 * 2);
  unsigned short* Am = (unsigned short*)carve((size_t)RB_PAD * 2048 * 2);
  unsigned short* Bh = (unsigned short*)carve((size_t)8192 * 8 * 2);
  unsigned short* Bm = (unsigned short*)carve((size_t)8192 * 8 * 2);

  // CSR build (recomputed every call — deterministic, no cross-call state)
  hipMemsetAsync(deg, 0, (size_t)NN * 4, stream);
  hipMemsetAsync(cur, 0, (size_t)NN * 4, stream);
  count_deg<<<(NE + 255) / 256, 256, 0, stream>>>(ei, deg);
  scan_partial<<<SCAN_B, SCAN_T, 0, stream>>>(deg, rowp, bsum);
  scan_bsums<<<1, 128, 0, stream>>>(bsum, boff, rowp);
  scan_add<<<SCAN_B, SCAN_T, 0, stream>>>(rowp, boff);
  scatter_src<<<(NE + 255) / 256, 256, 0, stream>>>(ei, rowp, cur, colsrc);

  // layer-0 input split + both layers' weight prep
  prep_a<<<RB_CNT, 256, 0, stream>>>(x, Ah, Am);
  prep_w<<<32, 256, 0, stream>>>(Wl[0], Wr[0], Wl[1], Wr[1], Bh, Bm);

  for (int l = 0; l < 2; l++) {
    dual_gemm_mfma<<<(NN + 31) / 32, 256, 0, stream>>>(
        Ah, Am, Bh + (size_t)l * 4096 * 8, Bm + (size_t)l * 4096 * 8,
        bl[l], br[l], xlb, xrb);
    if (l == 0) {
      fused_edge_agg<1><<<(NN * 32 + 255) / 256, 256, 0, stream>>>(
          rowp, colsrc, xlb, xrb, att[l], bias[l], gam[l], bet[l], out, Ah, Am);
    } else {
      fused_edge_agg<0><<<(NN * 32 + 255) / 256, 256, 0, stream>>>(
          rowp, colsrc, xlb, xrb, att[l], bias[l], gam[l], bet[l], out, Ah, Am);
    }
  }
}

// Round 15
// 196.002 us; speedup vs baseline: 2.3328x; 1.1270x over previous
//
#include <hip/hip_runtime.h>

#define NN 50000
#define NN_PAD 50016  // grid-covered row pad (guard-free GEMM stores)
#define NE 600000
#define DD 128
#define NH 4
#define RB_CNT 3125   // NN/16 (exact)
#define RB_PAD 3128

#define SCAN_T 512
#define SCAN_B ((NN + SCAN_T - 1) / SCAN_T)

#define LOG2E 1.44269504088896340736f

typedef short s16x8 __attribute__((ext_vector_type(8)));
typedef float f32x4 __attribute__((ext_vector_type(4)));

// fp32 -> bf16 (RNE) and back
__device__ __forceinline__ unsigned short bfh(float f) {
  unsigned u = __float_as_uint(f);
  return (unsigned short)((u + 0x7fffu + ((u >> 16) & 1u)) >> 16);
}
__device__ __forceinline__ float bff(unsigned short h) {
  return __uint_as_float(((unsigned)h) << 16);
}

// cross-lane add via DPP. 0xB1 quad xor1, 0x4E quad xor2, 0x141 row_half_mirror,
// 0x124/0x128 row_ror:4/:8.
template <int CTRL>
__device__ __forceinline__ float dpp_add(float x) {
  int y = __builtin_amdgcn_update_dpp(0, __float_as_int(x), CTRL, 0xf, 0xf, true);
  return x + __int_as_float(y);
}

// ---------- CSR build ----------
__global__ void count_deg(const int* __restrict__ ei, int* __restrict__ deg) {
  int e = blockIdx.x * 256 + threadIdx.x;
  if (e < NE) atomicAdd(deg + ei[NE + e], 1);
}

__global__ __launch_bounds__(SCAN_T) void scan_partial(
    const int* __restrict__ deg, int* __restrict__ rowp, int* __restrict__ bsum) {
  __shared__ int buf[SCAN_T];
  int b = blockIdx.x, t = threadIdx.x;
  int i = b * SCAN_T + t;
  int v = (i < NN) ? deg[i] : 0;
  buf[t] = v;
  __syncthreads();
  for (int o = 1; o < SCAN_T; o <<= 1) {
    int add = (t >= o) ? buf[t - o] : 0;
    __syncthreads();
    buf[t] += add;
    __syncthreads();
  }
  if (i < NN) rowp[i] = buf[t] - v;
  if (t == SCAN_T - 1) bsum[b] = buf[t];
}

__global__ __launch_bounds__(128) void scan_bsums(
    int* __restrict__ bsum, int* __restrict__ boff, int* __restrict__ rowp) {
  __shared__ int buf[128];
  int t = threadIdx.x;
  int v = (t < SCAN_B) ? bsum[t] : 0;
  buf[t] = v;
  __syncthreads();
  for (int o = 1; o < 128; o <<= 1) {
    int add = (t >= o) ? buf[t - o] : 0;
    __syncthreads();
    buf[t] += add;
    __syncthreads();
  }
  if (t < SCAN_B) boff[t] = buf[t] - v;
  if (t == 127) rowp[NN] = buf[t];
}

// finalize rowp AND seed cur=rowp (kills the cur memset + rowp read in scatter)
__global__ __launch_bounds__(SCAN_T) void scan_add(
    int* __restrict__ rowp, const int* __restrict__ boff, int* __restrict__ cur) {
  int b = blockIdx.x, t = threadIdx.x;
  int i = b * SCAN_T + t;
  if (i < NN) {
    int v = rowp[i] + boff[b];
    rowp[i] = v;
    cur[i] = v;
  }
}

// store src * 256 (bf16 row byte-stride); cur holds absolute positions
__global__ void scatter_src(const int* __restrict__ ei,
                            int* __restrict__ cur, int* __restrict__ colsrc) {
  int e = blockIdx.x * 256 + threadIdx.x;
  if (e < NE) {
    int d = ei[NE + e];
    int p = atomicAdd(cur + d, 1);
    colsrc[p] = ei[e] << 8;
  }
}

// ---------- prep (one dispatch): A fragments + both layers' W fragments ----------
__global__ __launch_bounds__(256) void prep_all(
    const float* __restrict__ h,
    const float* __restrict__ Wl0, const float* __restrict__ Wr0,
    const float* __restrict__ Wl1, const float* __restrict__ Wr1,
    unsigned short* __restrict__ Ah, unsigned short* __restrict__ Am,
    unsigned short* __restrict__ Bh, unsigned short* __restrict__ Bm) {
  int b = blockIdx.x;
  if (b < RB_CNT) {
    int tid = b * 256 + threadIdx.x;
    int lr = tid & 15;
    int g = (tid >> 4) & 3;
    int kt = (tid >> 6) & 3;
    int rb = tid >> 8;
    int row = rb * 16 + lr;
    const float* p = h + (size_t)row * DD + kt * 32 + 4 * g;
    float4 f0 = *(const float4*)(p);
    float4 f1 = *(const float4*)(p + 16);
    float fs[8] = {f0.x, f0.y, f0.z, f0.w, f1.x, f1.y, f1.z, f1.w};
    s16x8 hi, mid;
#pragma unroll
    for (int e = 0; e < 8; e++) {
      unsigned short hh = bfh(fs[e]);
      hi[e] = (short)hh;
      mid[e] = (short)bfh(fs[e] - bff(hh));
    }
    *(s16x8*)(Ah + (size_t)tid * 8) = hi;
    *(s16x8*)(Am + (size_t)tid * 8) = mid;
  } else {
    int tid = (b - RB_CNT) * 256 + threadIdx.x;   // 0..8191
    int lay = tid >> 12;
    int t = tid & 4095;
    int lr = t & 15;
    int g = (t >> 4) & 3;
    int kt = (t >> 6) & 3;
    int ct = t >> 8;
    int col = ct * 16 + lr;
    const float* W = (col < DD) ? (lay ? Wl1 : Wl0) : (lay ? Wr1 : Wr0);
    int cc = (col < DD) ? col : col - DD;
    s16x8 hi, mid;
#pragma unroll
    for (int e = 0; e < 8; e++) {
      int k = kt * 32 + ((e >> 2) << 4) + 4 * g + (e & 3);
      float w = W[(size_t)k * DD + cc];
      unsigned short hh = bfh(w);
      hi[e] = (short)hh;
      mid[e] = (short)bfh(w - bff(hh));
    }
    *(s16x8*)(Bh + (size_t)tid * 8) = hi;
    *(s16x8*)(Bm + (size_t)tid * 8) = mid;
  }
}

// ---------- dual GEMM: split-bf16 MFMA; guard-free bf16 stores (padded rows) ----------
__global__ __launch_bounds__(256, 2) void dual_gemm_mfma(
    const unsigned short* __restrict__ Ah, const unsigned short* __restrict__ Am,
    const unsigned short* __restrict__ Bh, const unsigned short* __restrict__ Bm,
    const float* __restrict__ blv, const float* __restrict__ brv,
    unsigned short* __restrict__ xlb, unsigned short* __restrict__ xrb) {
  const int tid = threadIdx.x;
  const int lane = tid & 63;
  const int wv = tid >> 6;
  const int lr = lane & 15;
  const int g = lane >> 4;
  const int rb0 = blockIdx.x * 2;

  f32x4 acc[2][4];
#pragma unroll
  for (int rt = 0; rt < 2; rt++)
#pragma unroll
    for (int nt = 0; nt < 4; nt++)
#pragma unroll
      for (int e = 0; e < 4; e++) acc[rt][nt][e] = 0.f;

#pragma unroll
  for (int kt = 0; kt < 4; kt++) {
    s16x8 ah[2], am[2], bh[4], bm[4];
#pragma unroll
    for (int rt = 0; rt < 2; rt++) {
      size_t off = ((((size_t)((rb0 + rt) * 4 + kt)) * 4 + g) * 16 + lr) * 8;
      ah[rt] = *(const s16x8*)(Ah + off);
      am[rt] = *(const s16x8*)(Am + off);
    }
#pragma unroll
    for (int nt = 0; nt < 4; nt++) {
      int ct = wv * 4 + nt;
      size_t off = ((((size_t)(ct * 4 + kt)) * 4 + g) * 16 + lr) * 8;
      bh[nt] = *(const s16x8*)(Bh + off);
      bm[nt] = *(const s16x8*)(Bm + off);
    }
#pragma unroll
    for (int rt = 0; rt < 2; rt++)
#pragma unroll
      for (int nt = 0; nt < 4; nt++) {
        acc[rt][nt] = __builtin_amdgcn_mfma_f32_16x16x32_bf16(ah[rt], bh[nt], acc[rt][nt], 0, 0, 0);
        acc[rt][nt] = __builtin_amdgcn_mfma_f32_16x16x32_bf16(ah[rt], bm[nt], acc[rt][nt], 0, 0, 0);
        acc[rt][nt] = __builtin_amdgcn_mfma_f32_16x16x32_bf16(am[rt], bh[nt], acc[rt][nt], 0, 0, 0);
      }
  }

#pragma unroll
  for (int nt = 0; nt < 4; nt++) {
    int col = wv * 64 + nt * 16 + lr;
    unsigned short* dst = (col < DD) ? (xlb + col) : (xrb + (col - DD));
    float bv = (col < DD) ? blv[col] : brv[col - DD];
#pragma unroll
    for (int rt = 0; rt < 2; rt++) {
      int rowb = blockIdx.x * 32 + rt * 16 + 4 * g;
#pragma unroll
      for (int r = 0; r < 4; r++)
        dst[(size_t)(rowb + r) * DD] = bfh(acc[rt][nt][r] + bv);   // rows < NN_PAD
    }
  }
}

// ---------- fused edge path v6: half-wave per node, 4-edge chunks ----------
// 4 colsrc + 4 gathers in flight per iteration (latency hiding), ~3 iters/node.
template <int SPLIT>
__global__ __launch_bounds__(256) void fused_edge_agg(
    const int* __restrict__ rowp, const int* __restrict__ colsrc,
    const unsigned short* __restrict__ xlb, const unsigned short* __restrict__ xrb,
    const float* __restrict__ att, const float* __restrict__ bias,
    const float* __restrict__ gam, const float* __restrict__ bet,
    float* __restrict__ out, unsigned short* __restrict__ Oh,
    unsigned short* __restrict__ Om) {
  int node = (blockIdx.x * 256 + threadIdx.x) >> 5;   // half-wave id
  if (node >= NN) return;
  int il = threadIdx.x & 31;
  int d0 = il << 2;                       // 4 dims per lane; head = il>>3

  ushort4 xru = *(const ushort4*)(xrb + (size_t)node * DD + d0);
  float4 xrv; xrv.x = bff(xru.x); xrv.y = bff(xru.y);
  xrv.z = bff(xru.z); xrv.w = bff(xru.w);
  float4 atv = *(const float4*)(att + d0);
  atv.x *= LOG2E; atv.y *= LOG2E; atv.z *= LOG2E; atv.w *= LOG2E;
  int j0 = rowp[node];
  int j1 = rowp[node + 1];

  float den = 0.f;
  float a0 = 0.f, a1 = 0.f, a2 = 0.f, a3 = 0.f;
  const char* xlb8 = (const char*)xlb;
  const int goff = il << 3;               // 8B per lane within row

  for (int j = j0; j < j1; j += 4) {
    bool v1 = (j + 1) < j1, v2 = (j + 2) < j1, v3 = (j + 3) < j1;
    int s0 = colsrc[j];                   // pre-scaled by 256
    int s1 = colsrc[v1 ? j + 1 : j];
    int s2 = colsrc[v2 ? j + 2 : j];
    int s3 = colsrc[v3 ? j + 3 : j];
    ushort4 g0 = *(const ushort4*)(xlb8 + (size_t)(unsigned)(s0 + goff));
    ushort4 g1 = *(const ushort4*)(xlb8 + (size_t)(unsigned)(s1 + goff));
    ushort4 g2 = *(const ushort4*)(xlb8 + (size_t)(unsigned)(s2 + goff));
    ushort4 g3 = *(const ushort4*)(xlb8 + (size_t)(unsigned)(s3 + goff));
    float x00 = bff(g0.x), x01 = bff(g0.y), x02 = bff(g0.z), x03 = bff(g0.w);
    float x10 = bff(g1.x), x11 = bff(g1.y), x12 = bff(g1.z), x13 = bff(g1.w);
    float x20 = bff(g2.x), x21 = bff(g2.y), x22 = bff(g2.z), x23 = bff(g2.w);
    float x30 = bff(g3.x), x31 = bff(g3.y), x32 = bff(g3.z), x33 = bff(g3.w);

    float t0, t1, t2, t3;
    t0 = x00 + xrv.x; t1 = x01 + xrv.y; t2 = x02 + xrv.z; t3 = x03 + xrv.w;
    t0 = fmaxf(t0, 0.2f * t0); t1 = fmaxf(t1, 0.2f * t1);
    t2 = fmaxf(t2, 0.2f * t2); t3 = fmaxf(t3, 0.2f * t3);
    float p0 = (t0 * atv.x + t1 * atv.y) + (t2 * atv.z + t3 * atv.w);
    t0 = x10 + xrv.x; t1 = x11 + xrv.y; t2 = x12 + xrv.z; t3 = x13 + xrv.w;
    t0 = fmaxf(t0, 0.2f * t0); t1 = fmaxf(t1, 0.2f * t1);
    t2 = fmaxf(t2, 0.2f * t2); t3 = fmaxf(t3, 0.2f * t3);
    float p1 = (t0 * atv.x + t1 * atv.y) + (t2 * atv.z + t3 * atv.w);
    t0 = x20 + xrv.x; t1 = x21 + xrv.y; t2 = x22 + xrv.z; t3 = x23 + xrv.w;
    t0 = fmaxf(t0, 0.2f * t0); t1 = fmaxf(t1, 0.2f * t1);
    t2 = fmaxf(t2, 0.2f * t2); t3 = fmaxf(t3, 0.2f * t3);
    float p2 = (t0 * atv.x + t1 * atv.y) + (t2 * atv.z + t3 * atv.w);
    t0 = x30 + xrv.x; t1 = x31 + xrv.y; t2 = x32 + xrv.z; t3 = x33 + xrv.w;
    t0 = fmaxf(t0, 0.2f * t0); t1 = fmaxf(t1, 0.2f * t1);
    t2 = fmaxf(t2, 0.2f * t2); t3 = fmaxf(t3, 0.2f * t3);
    float p3 = (t0 * atv.x + t1 * atv.y) + (t2 * atv.z + t3 * atv.w);

    // 8-lane (per-head) reduces — 4 independent chains pipeline in the VALU
    p0 = dpp_add<0xB1>(p0);  p1 = dpp_add<0xB1>(p1);
    p2 = dpp_add<0xB1>(p2);  p3 = dpp_add<0xB1>(p3);
    p0 = dpp_add<0x4E>(p0);  p1 = dpp_add<0x4E>(p1);
    p2 = dpp_add<0x4E>(p2);  p3 = dpp_add<0x4E>(p3);
    p0 = dpp_add<0x141>(p0); p1 = dpp_add<0x141>(p1);
    p2 = dpp_add<0x141>(p2); p3 = dpp_add<0x141>(p3);

    float w0 = exp2f(p0);
    float w1 = v1 ? exp2f(p1) : 0.f;
    float w2 = v2 ? exp2f(p2) : 0.f;
    float w3 = v3 ? exp2f(p3) : 0.f;
    den += (w0 + w1) + (w2 + w3);
    a0 += (w0 * x00 + w1 * x10) + (w2 * x20 + w3 * x30);
    a1 += (w0 * x01 + w1 * x11) + (w2 * x21 + w3 * x31);
    a2 += (w0 * x02 + w1 * x12) + (w2 * x22 + w3 * x32);
    a3 += (w0 * x03 + w1 * x13) + (w2 * x23 + w3 * x33);
  }

  float inv = 1.f / (den + 1e-16f);
  float4 bi = *(const float4*)(bias + d0);
  float vx0 = a0 * inv + bi.x, vx1 = a1 * inv + bi.y;
  float vx2 = a2 * inv + bi.z, vx3 = a3 * inv + bi.w;

  // LayerNorm over 128 dims within the 32-lane half
  float s1 = (vx0 + vx1) + (vx2 + vx3);
  float s2 = (vx0 * vx0 + vx1 * vx1) + (vx2 * vx2 + vx3 * vx3);
  s1 = dpp_add<0xB1>(s1);  s2 = dpp_add<0xB1>(s2);
  s1 = dpp_add<0x4E>(s1);  s2 = dpp_add<0x4E>(s2);
  s1 = dpp_add<0x124>(s1); s2 = dpp_add<0x124>(s2);
  s1 = dpp_add<0x128>(s1); s2 = dpp_add<0x128>(s2);
  s1 += __shfl_xor(s1, 16); s2 += __shfl_xor(s2, 16);
  float mean = s1 * (1.f / 128.f);
  float var = s2 * (1.f / 128.f) - mean * mean;
  float rstd = rsqrtf(var + 1e-5f);
  float4 gm = *(const float4*)(gam + d0);
  float4 bt = *(const float4*)(bet + d0);
  float n0 = (vx0 - mean) * rstd * gm.x + bt.x;
  float n1 = (vx1 - mean) * rstd * gm.y + bt.y;
  float n2 = (vx2 - mean) * rstd * gm.z + bt.z;
  float n3 = (vx3 - mean) * rstd * gm.w + bt.w;
  n0 = n0 > 0.f ? n0 : expf(n0) - 1.f;
  n1 = n1 > 0.f ? n1 : expf(n1) - 1.f;
  n2 = n2 > 0.f ? n2 : expf(n2) - 1.f;
  n3 = n3 > 0.f ? n3 : expf(n3) - 1.f;

  if (SPLIT) {
    int rb = node >> 4, lr16 = node & 15;
    int kt = d0 >> 5;
    int g = (d0 & 15) >> 2;
    int e0 = ((d0 >> 4) & 1) << 2;
    size_t off = ((((size_t)(rb * 4 + kt)) * 4 + g) * 16 + lr16) * 8 + e0;
    unsigned short h0 = bfh(n0), h1 = bfh(n1), h2 = bfh(n2), h3 = bfh(n3);
    ushort4 hv; hv.x = h0; hv.y = h1; hv.z = h2; hv.w = h3;
    ushort4 mv;
    mv.x = bfh(n0 - bff(h0)); mv.y = bfh(n1 - bff(h1));
    mv.z = bfh(n2 - bff(h2)); mv.w = bfh(n3 - bff(h3));
    *(ushort4*)(Oh + off) = hv;
    *(ushort4*)(Om + off) = mv;
  } else {
    float4 o; o.x = n0; o.y = n1; o.z = n2; o.w = n3;
    *(float4*)(out + (size_t)node * DD + d0) = o;
  }
}

extern "C" void kernel_launch(void* const* d_in, const int* in_sizes, int n_in,
                              void* d_out, int out_size, void* d_ws, size_t ws_size,
                              hipStream_t stream) {
  const float* x  = (const float*)d_in[0];
  const int*   ei = (const int*)d_in[1];
  const float* Wl[2]   = {(const float*)d_in[2],  (const float*)d_in[10]};
  const float* bl[2]   = {(const float*)d_in[3],  (const float*)d_in[11]};
  const float* Wr[2]   = {(const float*)d_in[4],  (const float*)d_in[12]};
  const float* br[2]   = {(const float*)d_in[5],  (const float*)d_in[13]};
  const float* att[2]  = {(const float*)d_in[6],  (const float*)d_in[14]};
  const float* bias[2] = {(const float*)d_in[7],  (const float*)d_in[15]};
  const float* gam[2]  = {(const float*)d_in[8],  (const float*)d_in[16]};
  const float* bet[2]  = {(const float*)d_in[9],  (const float*)d_in[17]};
  float* out = (float*)d_out;

  char* w = (char*)d_ws;
  auto carve = [&](size_t bytes) {
    char* p = w;
    w += (bytes + 255) & ~(size_t)255;
    return p;
  };
  unsigned short* xlb = (unsigned short*)carve((size_t)NN_PAD * DD * 2);
  unsigned short* xrb = (unsigned short*)carve((size_t)NN_PAD * DD * 2);
  int*   deg    = (int*)carve((size_t)NN * 4);
  int*   cur    = (int*)carve((size_t)NN * 4);
  int*   rowp   = (int*)carve((size_t)(NN + 1) * 4);
  int*   colsrc = (int*)carve((size_t)NE * 4);
  int*   bsum   = (int*)carve((size_t)SCAN_B * 4);
  int*   boff   = (int*)carve((size_t)SCAN_B * 4);
  unsigned short* Ah = (unsigned short*)carve((size_t)RB_PAD * 2048 * 2);
  unsigned short* Am = (unsigned short*)carve((size_t)RB_PAD * 2048 * 2);
  unsigned short* Bh = (unsigned short*)carve((size_t)8192 * 8 * 2);
  unsigned short* Bm = (unsigned short*)carve((size_t)8192 * 8 * 2);

  // CSR build (recomputed every call — deterministic, no cross-call state)
  hipMemsetAsync(deg, 0, (size_t)NN * 4, stream);
  count_deg<<<(NE + 255) / 256, 256, 0, stream>>>(ei, deg);
  scan_partial<<<SCAN_B, SCAN_T, 0, stream>>>(deg, rowp, bsum);
  scan_bsums<<<1, 128, 0, stream>>>(bsum, boff, rowp);
  scan_add<<<SCAN_B, SCAN_T, 0, stream>>>(rowp, boff, cur);
  scatter_src<<<(NE + 255) / 256, 256, 0, stream>>>(ei, cur, colsrc);

  // layer-0 A split + both layers' W split, one dispatch
  prep_all<<<RB_CNT + 32, 256, 0, stream>>>(x, Wl[0], Wr[0], Wl[1], Wr[1],
                                            Ah, Am, Bh, Bm);

  for (int l = 0; l < 2; l++) {
    dual_gemm_mfma<<<(NN + 31) / 32, 256, 0, stream>>>(
        Ah, Am, Bh + (size_t)l * 4096 * 8, Bm + (size_t)l * 4096 * 8,
        bl[l], br[l], xlb, xrb);
    if (l == 0) {
      fused_edge_agg<1><<<(NN * 32 + 255) / 256, 256, 0, stream>>>(
          rowp, colsrc, xlb, xrb, att[l], bias[l], gam[l], bet[l], out, Ah, Am);
    } else {
      fused_edge_agg<0><<<(NN * 32 + 255) / 256, 256, 0, stream>>>(
          rowp, colsrc, xlb, xrb, att[l], bias[l], gam[l], bet[l], out, Ah, Am);
    }
  }
}

// Round 16
// 193.818 us; speedup vs baseline: 2.3591x; 1.0113x over previous
//
#include <hip/hip_runtime.h>

#define NN 50000
#define NN_PAD 50016  // grid-covered row pad (guard-free GEMM stores)
#define NE 600000
#define DD 128
#define NH 4
#define RB_CNT 3125   // NN/16 (exact)
#define RB_PAD 3128

#define SCAN_T 512
#define SCAN_B ((NN + SCAN_T - 1) / SCAN_T)

#define LOG2E 1.44269504088896340736f

typedef short s16x8 __attribute__((ext_vector_type(8)));
typedef float f32x4 __attribute__((ext_vector_type(4)));

// fp32 -> bf16 (RNE) and back
__device__ __forceinline__ unsigned short bfh(float f) {
  unsigned u = __float_as_uint(f);
  return (unsigned short)((u + 0x7fffu + ((u >> 16) & 1u)) >> 16);
}
__device__ __forceinline__ float bff(unsigned short h) {
  return __uint_as_float(((unsigned)h) << 16);
}

// cross-lane add via DPP. 0xB1 quad xor1, 0x4E quad xor2, 0x141 row_half_mirror,
// 0x124/0x128 row_ror:4/:8.
template <int CTRL>
__device__ __forceinline__ float dpp_add(float x) {
  int y = __builtin_amdgcn_update_dpp(0, __float_as_int(x), CTRL, 0xf, 0xf, true);
  return x + __int_as_float(y);
}

// ---------- CSR build ----------
__global__ void count_deg(const int* __restrict__ ei, int* __restrict__ deg) {
  int e = blockIdx.x * 256 + threadIdx.x;
  if (e < NE) atomicAdd(deg + ei[NE + e], 1);
}

__global__ __launch_bounds__(SCAN_T) void scan_partial(
    const int* __restrict__ deg, int* __restrict__ rowp, int* __restrict__ bsum) {
  __shared__ int buf[SCAN_T];
  int b = blockIdx.x, t = threadIdx.x;
  int i = b * SCAN_T + t;
  int v = (i < NN) ? deg[i] : 0;
  buf[t] = v;
  __syncthreads();
  for (int o = 1; o < SCAN_T; o <<= 1) {
    int add = (t >= o) ? buf[t - o] : 0;
    __syncthreads();
    buf[t] += add;
    __syncthreads();
  }
  if (i < NN) rowp[i] = buf[t] - v;
  if (t == SCAN_T - 1) bsum[b] = buf[t];
}

// fused: block-sum scan (redundant per block) + rowp finalize + cur seed
__global__ __launch_bounds__(SCAN_T) void scan_finish(
    const int* __restrict__ bsum, int* __restrict__ rowp, int* __restrict__ cur) {
  __shared__ int sb[SCAN_T];
  int b = blockIdx.x, t = threadIdx.x;
  int v = (t < SCAN_B) ? bsum[t] : 0;
  sb[t] = v;
  __syncthreads();
  for (int o = 1; o < SCAN_T; o <<= 1) {
    int add = (t >= o) ? sb[t - o] : 0;
    __syncthreads();
    sb[t] += add;
    __syncthreads();
  }
  int boff = sb[b] - bsum[b];          // exclusive prefix at this block (b < SCAN_B)
  int i = b * SCAN_T + t;
  if (i < NN) {
    int r = rowp[i] + boff;
    rowp[i] = r;
    cur[i] = r;
  }
  if (b == 0 && t == 0) rowp[NN] = sb[SCAN_B - 1];   // total == NE
}

// store src * 256 (bf16 row byte-stride); cur holds absolute positions
__global__ void scatter_src(const int* __restrict__ ei,
                            int* __restrict__ cur, int* __restrict__ colsrc) {
  int e = blockIdx.x * 256 + threadIdx.x;
  if (e < NE) {
    int d = ei[NE + e];
    int p = atomicAdd(cur + d, 1);
    colsrc[p] = ei[e] << 8;
  }
}

// ---------- prep (one dispatch): A fragments + both layers' W fragments ----------
__global__ __launch_bounds__(256) void prep_all(
    const float* __restrict__ h,
    const float* __restrict__ Wl0, const float* __restrict__ Wr0,
    const float* __restrict__ Wl1, const float* __restrict__ Wr1,
    unsigned short* __restrict__ Ah, unsigned short* __restrict__ Am,
    unsigned short* __restrict__ Bh, unsigned short* __restrict__ Bm) {
  int b = blockIdx.x;
  if (b < RB_CNT) {
    int tid = b * 256 + threadIdx.x;
    int lr = tid & 15;
    int g = (tid >> 4) & 3;
    int kt = (tid >> 6) & 3;
    int rb = tid >> 8;
    int row = rb * 16 + lr;
    const float* p = h + (size_t)row * DD + kt * 32 + 4 * g;
    float4 f0 = *(const float4*)(p);
    float4 f1 = *(const float4*)(p + 16);
    float fs[8] = {f0.x, f0.y, f0.z, f0.w, f1.x, f1.y, f1.z, f1.w};
    s16x8 hi, mid;
#pragma unroll
    for (int e = 0; e < 8; e++) {
      unsigned short hh = bfh(fs[e]);
      hi[e] = (short)hh;
      mid[e] = (short)bfh(fs[e] - bff(hh));
    }
    *(s16x8*)(Ah + (size_t)tid * 8) = hi;
    *(s16x8*)(Am + (size_t)tid * 8) = mid;
  } else {
    int tid = (b - RB_CNT) * 256 + threadIdx.x;   // 0..8191
    int lay = tid >> 12;
    int t = tid & 4095;
    int lr = t & 15;
    int g = (t >> 4) & 3;
    int kt = (t >> 6) & 3;
    int ct = t >> 8;
    int col = ct * 16 + lr;
    const float* W = (col < DD) ? (lay ? Wl1 : Wl0) : (lay ? Wr1 : Wr0);
    int cc = (col < DD) ? col : col - DD;
    s16x8 hi, mid;
#pragma unroll
    for (int e = 0; e < 8; e++) {
      int k = kt * 32 + ((e >> 2) << 4) + 4 * g + (e & 3);
      float w = W[(size_t)k * DD + cc];
      unsigned short hh = bfh(w);
      hi[e] = (short)hh;
      mid[e] = (short)bfh(w - bff(hh));
    }
    *(s16x8*)(Bh + (size_t)tid * 8) = hi;
    *(s16x8*)(Bm + (size_t)tid * 8) = mid;
  }
}

// ---------- dual GEMM: split-bf16 MFMA; 3 waves/SIMD for latency hiding ----------
__global__ __launch_bounds__(256, 3) void dual_gemm_mfma(
    const unsigned short* __restrict__ Ah, const unsigned short* __restrict__ Am,
    const unsigned short* __restrict__ Bh, const unsigned short* __restrict__ Bm,
    const float* __restrict__ blv, const float* __restrict__ brv,
    unsigned short* __restrict__ xlb, unsigned short* __restrict__ xrb) {
  const int tid = threadIdx.x;
  const int lane = tid & 63;
  const int wv = tid >> 6;
  const int lr = lane & 15;
  const int g = lane >> 4;
  const int rb0 = blockIdx.x * 2;

  f32x4 acc[2][4];
#pragma unroll
  for (int rt = 0; rt < 2; rt++)
#pragma unroll
    for (int nt = 0; nt < 4; nt++)
#pragma unroll
      for (int e = 0; e < 4; e++) acc[rt][nt][e] = 0.f;

#pragma unroll
  for (int kt = 0; kt < 4; kt++) {
    s16x8 ah[2], am[2], bh[4], bm[4];
#pragma unroll
    for (int rt = 0; rt < 2; rt++) {
      size_t off = ((((size_t)((rb0 + rt) * 4 + kt)) * 4 + g) * 16 + lr) * 8;
      ah[rt] = *(const s16x8*)(Ah + off);
      am[rt] = *(const s16x8*)(Am + off);
    }
#pragma unroll
    for (int nt = 0; nt < 4; nt++) {
      int ct = wv * 4 + nt;
      size_t off = ((((size_t)(ct * 4 + kt)) * 4 + g) * 16 + lr) * 8;
      bh[nt] = *(const s16x8*)(Bh + off);
      bm[nt] = *(const s16x8*)(Bm + off);
    }
#pragma unroll
    for (int rt = 0; rt < 2; rt++)
#pragma unroll
      for (int nt = 0; nt < 4; nt++) {
        acc[rt][nt] = __builtin_amdgcn_mfma_f32_16x16x32_bf16(ah[rt], bh[nt], acc[rt][nt], 0, 0, 0);
        acc[rt][nt] = __builtin_amdgcn_mfma_f32_16x16x32_bf16(ah[rt], bm[nt], acc[rt][nt], 0, 0, 0);
        acc[rt][nt] = __builtin_amdgcn_mfma_f32_16x16x32_bf16(am[rt], bh[nt], acc[rt][nt], 0, 0, 0);
      }
  }

#pragma unroll
  for (int nt = 0; nt < 4; nt++) {
    int col = wv * 64 + nt * 16 + lr;
    unsigned short* dst = (col < DD) ? (xlb + col) : (xrb + (col - DD));
    float bv = (col < DD) ? blv[col] : brv[col - DD];
#pragma unroll
    for (int rt = 0; rt < 2; rt++) {
      int rowb = blockIdx.x * 32 + rt * 16 + 4 * g;
#pragma unroll
      for (int r = 0; r < 4; r++)
        dst[(size_t)(rowb + r) * DD] = bfh(acc[rt][nt][r] + bv);   // rows < NN_PAD
    }
  }
}

// ---------- fused edge path v6: half-wave per node, 4-edge chunks ----------
template <int SPLIT>
__global__ __launch_bounds__(256) void fused_edge_agg(
    const int* __restrict__ rowp, const int* __restrict__ colsrc,
    const unsigned short* __restrict__ xlb, const unsigned short* __restrict__ xrb,
    const float* __restrict__ att, const float* __restrict__ bias,
    const float* __restrict__ gam, const float* __restrict__ bet,
    float* __restrict__ out, unsigned short* __restrict__ Oh,
    unsigned short* __restrict__ Om) {
  int node = (blockIdx.x * 256 + threadIdx.x) >> 5;   // half-wave id
  if (node >= NN) return;
  int il = threadIdx.x & 31;
  int d0 = il << 2;                       // 4 dims per lane; head = il>>3

  ushort4 xru = *(const ushort4*)(xrb + (size_t)node * DD + d0);
  float4 xrv; xrv.x = bff(xru.x); xrv.y = bff(xru.y);
  xrv.z = bff(xru.z); xrv.w = bff(xru.w);
  float4 atv = *(const float4*)(att + d0);
  atv.x *= LOG2E; atv.y *= LOG2E; atv.z *= LOG2E; atv.w *= LOG2E;
  int j0 = rowp[node];
  int j1 = rowp[node + 1];

  float den = 0.f;
  float a0 = 0.f, a1 = 0.f, a2 = 0.f, a3 = 0.f;
  const char* xlb8 = (const char*)xlb;
  const int goff = il << 3;               // 8B per lane within row

  for (int j = j0; j < j1; j += 4) {
    bool v1 = (j + 1) < j1, v2 = (j + 2) < j1, v3 = (j + 3) < j1;
    int s0 = colsrc[j];                   // pre-scaled by 256
    int s1 = colsrc[v1 ? j + 1 : j];
    int s2 = colsrc[v2 ? j + 2 : j];
    int s3 = colsrc[v3 ? j + 3 : j];
    ushort4 g0 = *(const ushort4*)(xlb8 + (size_t)(unsigned)(s0 + goff));
    ushort4 g1 = *(const ushort4*)(xlb8 + (size_t)(unsigned)(s1 + goff));
    ushort4 g2 = *(const ushort4*)(xlb8 + (size_t)(unsigned)(s2 + goff));
    ushort4 g3 = *(const ushort4*)(xlb8 + (size_t)(unsigned)(s3 + goff));
    float x00 = bff(g0.x), x01 = bff(g0.y), x02 = bff(g0.z), x03 = bff(g0.w);
    float x10 = bff(g1.x), x11 = bff(g1.y), x12 = bff(g1.z), x13 = bff(g1.w);
    float x20 = bff(g2.x), x21 = bff(g2.y), x22 = bff(g2.z), x23 = bff(g2.w);
    float x30 = bff(g3.x), x31 = bff(g3.y), x32 = bff(g3.z), x33 = bff(g3.w);

    float t0, t1, t2, t3;
    t0 = x00 + xrv.x; t1 = x01 + xrv.y; t2 = x02 + xrv.z; t3 = x03 + xrv.w;
    t0 = fmaxf(t0, 0.2f * t0); t1 = fmaxf(t1, 0.2f * t1);
    t2 = fmaxf(t2, 0.2f * t2); t3 = fmaxf(t3, 0.2f * t3);
    float p0 = (t0 * atv.x + t1 * atv.y) + (t2 * atv.z + t3 * atv.w);
    t0 = x10 + xrv.x; t1 = x11 + xrv.y; t2 = x12 + xrv.z; t3 = x13 + xrv.w;
    t0 = fmaxf(t0, 0.2f * t0); t1 = fmaxf(t1, 0.2f * t1);
    t2 = fmaxf(t2, 0.2f * t2); t3 = fmaxf(t3, 0.2f * t3);
    float p1 = (t0 * atv.x + t1 * atv.y) + (t2 * atv.z + t3 * atv.w);
    t0 = x20 + xrv.x; t1 = x21 + xrv.y; t2 = x22 + xrv.z; t3 = x23 + xrv.w;
    t0 = fmaxf(t0, 0.2f * t0); t1 = fmaxf(t1, 0.2f * t1);
    t2 = fmaxf(t2, 0.2f * t2); t3 = fmaxf(t3, 0.2f * t3);
    float p2 = (t0 * atv.x + t1 * atv.y) + (t2 * atv.z + t3 * atv.w);
    t0 = x30 + xrv.x; t1 = x31 + xrv.y; t2 = x32 + xrv.z; t3 = x33 + xrv.w;
    t0 = fmaxf(t0, 0.2f * t0); t1 = fmaxf(t1, 0.2f * t1);
    t2 = fmaxf(t2, 0.2f * t2); t3 = fmaxf(t3, 0.2f * t3);
    float p3 = (t0 * atv.x + t1 * atv.y) + (t2 * atv.z + t3 * atv.w);

    // 8-lane (per-head) reduces — 4 independent chains pipeline in the VALU
    p0 = dpp_add<0xB1>(p0);  p1 = dpp_add<0xB1>(p1);
    p2 = dpp_add<0xB1>(p2);  p3 = dpp_add<0xB1>(p3);
    p0 = dpp_add<0x4E>(p0);  p1 = dpp_add<0x4E>(p1);
    p2 = dpp_add<0x4E>(p2);  p3 = dpp_add<0x4E>(p3);
    p0 = dpp_add<0x141>(p0); p1 = dpp_add<0x141>(p1);
    p2 = dpp_add<0x141>(p2); p3 = dpp_add<0x141>(p3);

    float w0 = exp2f(p0);
    float w1 = v1 ? exp2f(p1) : 0.f;
    float w2 = v2 ? exp2f(p2) : 0.f;
    float w3 = v3 ? exp2f(p3) : 0.f;
    den += (w0 + w1) + (w2 + w3);
    a0 += (w0 * x00 + w1 * x10) + (w2 * x20 + w3 * x30);
    a1 += (w0 * x01 + w1 * x11) + (w2 * x21 + w3 * x31);
    a2 += (w0 * x02 + w1 * x12) + (w2 * x22 + w3 * x32);
    a3 += (w0 * x03 + w1 * x13) + (w2 * x23 + w3 * x33);
  }

  float inv = 1.f / (den + 1e-16f);
  float4 bi = *(const float4*)(bias + d0);
  float vx0 = a0 * inv + bi.x, vx1 = a1 * inv + bi.y;
  float vx2 = a2 * inv + bi.z, vx3 = a3 * inv + bi.w;

  // LayerNorm over 128 dims within the 32-lane half
  float s1 = (vx0 + vx1) + (vx2 + vx3);
  float s2 = (vx0 * vx0 + vx1 * vx1) + (vx2 * vx2 + vx3 * vx3);
  s1 = dpp_add<0xB1>(s1);  s2 = dpp_add<0xB1>(s2);
  s1 = dpp_add<0x4E>(s1);  s2 = dpp_add<0x4E>(s2);
  s1 = dpp_add<0x124>(s1); s2 = dpp_add<0x124>(s2);
  s1 = dpp_add<0x128>(s1); s2 = dpp_add<0x128>(s2);
  s1 += __shfl_xor(s1, 16); s2 += __shfl_xor(s2, 16);
  float mean = s1 * (1.f / 128.f);
  float var = s2 * (1.f / 128.f) - mean * mean;
  float rstd = rsqrtf(var + 1e-5f);
  float4 gm = *(const float4*)(gam + d0);
  float4 bt = *(const float4*)(bet + d0);
  float n0 = (vx0 - mean) * rstd * gm.x + bt.x;
  float n1 = (vx1 - mean) * rstd * gm.y + bt.y;
  float n2 = (vx2 - mean) * rstd * gm.z + bt.z;
  float n3 = (vx3 - mean) * rstd * gm.w + bt.w;
  n0 = n0 > 0.f ? n0 : expf(n0) - 1.f;
  n1 = n1 > 0.f ? n1 : expf(n1) - 1.f;
  n2 = n2 > 0.f ? n2 : expf(n2) - 1.f;
  n3 = n3 > 0.f ? n3 : expf(n3) - 1.f;

  if (SPLIT) {
    int rb = node >> 4, lr16 = node & 15;
    int kt = d0 >> 5;
    int g = (d0 & 15) >> 2;
    int e0 = ((d0 >> 4) & 1) << 2;
    size_t off = ((((size_t)(rb * 4 + kt)) * 4 + g) * 16 + lr16) * 8 + e0;
    unsigned short h0 = bfh(n0), h1 = bfh(n1), h2 = bfh(n2), h3 = bfh(n3);
    ushort4 hv; hv.x = h0; hv.y = h1; hv.z = h2; hv.w = h3;
    ushort4 mv;
    mv.x = bfh(n0 - bff(h0)); mv.y = bfh(n1 - bff(h1));
    mv.z = bfh(n2 - bff(h2)); mv.w = bfh(n3 - bff(h3));
    *(ushort4*)(Oh + off) = hv;
    *(ushort4*)(Om + off) = mv;
  } else {
    float4 o; o.x = n0; o.y = n1; o.z = n2; o.w = n3;
    *(float4*)(out + (size_t)node * DD + d0) = o;
  }
}

extern "C" void kernel_launch(void* const* d_in, const int* in_sizes, int n_in,
                              void* d_out, int out_size, void* d_ws, size_t ws_size,
                              hipStream_t stream) {
  const float* x  = (const float*)d_in[0];
  const int*   ei = (const int*)d_in[1];
  const float* Wl[2]   = {(const float*)d_in[2],  (const float*)d_in[10]};
  const float* bl[2]   = {(const float*)d_in[3],  (const float*)d_in[11]};
  const float* Wr[2]   = {(const float*)d_in[4],  (const float*)d_in[12]};
  const float* br[2]   = {(const float*)d_in[5],  (const float*)d_in[13]};
  const float* att[2]  = {(const float*)d_in[6],  (const float*)d_in[14]};
  const float* bias[2] = {(const float*)d_in[7],  (const float*)d_in[15]};
  const float* gam[2]  = {(const float*)d_in[8],  (const float*)d_in[16]};
  const float* bet[2]  = {(const float*)d_in[9],  (const float*)d_in[17]};
  float* out = (float*)d_out;

  char* w = (char*)d_ws;
  auto carve = [&](size_t bytes) {
    char* p = w;
    w += (bytes + 255) & ~(size_t)255;
    return p;
  };
  unsigned short* xlb = (unsigned short*)carve((size_t)NN_PAD * DD * 2);
  unsigned short* xrb = (unsigned short*)carve((size_t)NN_PAD * DD * 2);
  int*   deg    = (int*)carve((size_t)NN * 4);
  int*   cur    = (int*)carve((size_t)NN * 4);
  int*   rowp   = (int*)carve((size_t)(NN + 1) * 4);
  int*   colsrc = (int*)carve((size_t)NE * 4);
  int*   bsum   = (int*)carve((size_t)SCAN_B * 4);
  unsigned short* Ah = (unsigned short*)carve((size_t)RB_PAD * 2048 * 2);
  unsigned short* Am = (unsigned short*)carve((size_t)RB_PAD * 2048 * 2);
  unsigned short* Bh = (unsigned short*)carve((size_t)8192 * 8 * 2);
  unsigned short* Bm = (unsigned short*)carve((size_t)8192 * 8 * 2);

  // CSR build (recomputed every call — deterministic, no cross-call state)
  hipMemsetAsync(deg, 0, (size_t)NN * 4, stream);
  count_deg<<<(NE + 255) / 256, 256, 0, stream>>>(ei, deg);
  scan_partial<<<SCAN_B, SCAN_T, 0, stream>>>(deg, rowp, bsum);
  scan_finish<<<SCAN_B, SCAN_T, 0, stream>>>(bsum, rowp, cur);
  scatter_src<<<(NE + 255) / 256, 256, 0, stream>>>(ei, cur, colsrc);

  // layer-0 A split + both layers' W split, one dispatch
  prep_all<<<RB_CNT + 32, 256, 0, stream>>>(x, Wl[0], Wr[0], Wl[1], Wr[1],
                                            Ah, Am, Bh, Bm);

  for (int l = 0; l < 2; l++) {
    dual_gemm_mfma<<<(NN + 31) / 32, 256, 0, stream>>>(
        Ah, Am, Bh + (size_t)l * 4096 * 8, Bm + (size_t)l * 4096 * 8,
        bl[l], br[l], xlb, xrb);
    if (l == 0) {
      fused_edge_agg<1><<<(NN * 32 + 255) / 256, 256, 0, stream>>>(
          rowp, colsrc, xlb, xrb, att[l], bias[l], gam[l], bet[l], out, Ah, Am);
    } else {
      fused_edge_agg<0><<<(NN * 32 + 255) / 256, 256, 0, stream>>>(
          rowp, colsrc, xlb, xrb, att[l], bias[l], gam[l], bet[l], out, Ah, Am);
    }
  }
}